// Round 4
// baseline (1004.622 us; speedup 1.0000x reference)
//
#include <hip/hip_runtime.h>

typedef __bf16 bf16;
typedef __bf16 bf16x4 __attribute__((ext_vector_type(4)));
typedef __bf16 bf16x8 __attribute__((ext_vector_type(8)));
typedef float  f32x4  __attribute__((ext_vector_type(4)));

#define MFMA16(A_, B_, C_) __builtin_amdgcn_mfma_f32_16x16x32_bf16((A_), (B_), (C_), 0, 0, 0)

// ---- constants ----
#define BB 4
#define TT 2048
#define CC 1024
#define HH 16
#define DD 64
#define N_QKV (3 * CC)       // 3072
#define LDSS 68              // padded LDS row stride for attention tiles
#define BSTRIDE 36           // sB row stride: 72 B, 8B-aligned for b64 reads

static __device__ __forceinline__ void store_lds8(bf16* p, bf16x8 v) {
  bf16x4 lo, hi;
#pragma unroll
  for (int i = 0; i < 4; i++) { lo[i] = v[i]; hi[i] = v[i + 4]; }
  *(bf16x4*)p = lo;
  *(bf16x4*)(p + 4) = hi;
}

static __device__ __forceinline__ bf16x8 load_lds8(const bf16* p) {
  bf16x4 lo = *(const bf16x4*)p;
  bf16x4 hi = *(const bf16x4*)(p + 4);
  bf16x8 v;
#pragma unroll
  for (int i = 0; i < 4; i++) { v[i] = lo[i]; v[i + 4] = hi[i]; }
  return v;
}

static __device__ __forceinline__ float red16_max(float v) {
  v = fmaxf(v, __shfl_xor(v, 1, 64));
  v = fmaxf(v, __shfl_xor(v, 2, 64));
  v = fmaxf(v, __shfl_xor(v, 4, 64));
  v = fmaxf(v, __shfl_xor(v, 8, 64));
  return v;
}
static __device__ __forceinline__ float red16_sum(float v) {
  v += __shfl_xor(v, 1, 64);
  v += __shfl_xor(v, 2, 64);
  v += __shfl_xor(v, 4, 64);
  v += __shfl_xor(v, 8, 64);
  return v;
}

// -------------------- dtype sniff --------------------
// If the input is fp32, its uint16 low halves are ~uniform -> exponent-all-1
// patterns occur (~0.4%/elem). Genuine bf16 normal data never has exp=0xFF.
__global__ __launch_bounds__(256) void sniff_k(const unsigned short* __restrict__ u,
                                               int* __restrict__ flag) {
  __shared__ int s;
  if (threadIdx.x == 0) s = 0;
  __syncthreads();
  int c = 0;
  for (int i = threadIdx.x; i < 65536; i += 256)
    if ((u[i] & 0x7F80u) == 0x7F80u) c = 1;
  if (c) atomicOr(&s, 1);
  __syncthreads();
  if (threadIdx.x == 0) *flag = s;   // 1 = fp32 world, 0 = bf16 world
}

// ----- GEMM: C[M,N] = A[M,K](lda) @ W[K,N] row-major [+ bias], C stride ldc --
// AF/WF: these operands may be fp32 (branch on *flag). EPI=0: bf16 store (qkv).
// EPI=1: +bias, store fp32 or bf16 per flag.
template <int EPI, bool AF, bool WF>
__global__ __launch_bounds__(256) void gemm_nt(const void* __restrict__ Av,
                                               const void* __restrict__ Wv,
                                               const void* __restrict__ biasv,
                                               void* __restrict__ Cv,
                                               const int* __restrict__ flag,
                                               size_t aoff, size_t coff,
                                               int M, int N, int K,
                                               int lda, int ldc) {
  const int fl = *flag;
  const bool af32 = AF && (fl != 0);
  const bool wf32 = WF && (fl != 0);
  __shared__ __align__(16) bf16 sA[128 * 32];       // [m][k], stride 32
  __shared__ __align__(16) bf16 sB[128 * BSTRIDE];  // [n][k], stride 36
  const int tid = threadIdx.x;
  const int lane = tid & 63, wave = tid >> 6;
  const int quad = lane >> 4, l15 = lane & 15;
  const int wr = wave >> 1, wc = wave & 1;
  const int m0 = blockIdx.x * 128, n0 = blockIdx.y * 128;
  const int arow = tid >> 2;          // 0..63
  const int acol = (tid & 3) * 8;     // 0,8,16,24
  const int wk = tid >> 3;            // 0..31
  const int wn = (tid & 7) * 16;      // 0..112

  f32x4 acc[4][4];
#pragma unroll
  for (int i = 0; i < 4; i++)
#pragma unroll
    for (int j = 0; j < 4; j++) {
      f32x4 z = {0.f, 0.f, 0.f, 0.f};
      acc[i][j] = z;
    }

  const size_t abase0 = aoff + (size_t)(m0 + arow) * lda + acol;
  const size_t abase1 = abase0 + (size_t)64 * lda;

  for (int k0 = 0; k0 < K; k0 += 32) {
    bf16x8 a0, a1;
    if (af32) {
      const float* Af = (const float*)Av;
      f32x4 p00 = *(const f32x4*)(Af + abase0 + k0);
      f32x4 p01 = *(const f32x4*)(Af + abase0 + k0 + 4);
      f32x4 p10 = *(const f32x4*)(Af + abase1 + k0);
      f32x4 p11 = *(const f32x4*)(Af + abase1 + k0 + 4);
#pragma unroll
      for (int i = 0; i < 4; i++) {
        a0[i] = (bf16)p00[i]; a0[i + 4] = (bf16)p01[i];
        a1[i] = (bf16)p10[i]; a1[i + 4] = (bf16)p11[i];
      }
    } else {
      const bf16* Ab = (const bf16*)Av;
      a0 = *(const bf16x8*)(Ab + abase0 + k0);
      a1 = *(const bf16x8*)(Ab + abase1 + k0);
    }
    bf16 wreg[16];
    const size_t wbase = (size_t)(k0 + wk) * N + n0 + wn;
    if (wf32) {
      const float* Wf = (const float*)Wv;
      f32x4 q0 = *(const f32x4*)(Wf + wbase);
      f32x4 q1 = *(const f32x4*)(Wf + wbase + 4);
      f32x4 q2 = *(const f32x4*)(Wf + wbase + 8);
      f32x4 q3 = *(const f32x4*)(Wf + wbase + 12);
#pragma unroll
      for (int i = 0; i < 4; i++) {
        wreg[i] = (bf16)q0[i];      wreg[4 + i] = (bf16)q1[i];
        wreg[8 + i] = (bf16)q2[i];  wreg[12 + i] = (bf16)q3[i];
      }
    } else {
      const bf16* Wb = (const bf16*)Wv;
      bf16x8 w0 = *(const bf16x8*)(Wb + wbase);
      bf16x8 w1 = *(const bf16x8*)(Wb + wbase + 8);
#pragma unroll
      for (int i = 0; i < 8; i++) { wreg[i] = w0[i]; wreg[8 + i] = w1[i]; }
    }
    __syncthreads();
    *(bf16x8*)(sA + arow * 32 + acol) = a0;
    *(bf16x8*)(sA + (64 + arow) * 32 + acol) = a1;
#pragma unroll
    for (int i = 0; i < 16; i++)
      sB[(wn + i) * BSTRIDE + wk] = wreg[i];
    __syncthreads();

    bf16x8 af[4], bfr[4];
#pragma unroll
    for (int mi = 0; mi < 4; mi++)
      af[mi] = load_lds8(sA + (wr * 64 + mi * 16 + l15) * 32 + quad * 8);
#pragma unroll
    for (int ni = 0; ni < 4; ni++)
      bfr[ni] = load_lds8(sB + (wc * 64 + ni * 16 + l15) * BSTRIDE + quad * 8);
#pragma unroll
    for (int mi = 0; mi < 4; mi++)
#pragma unroll
      for (int ni = 0; ni < 4; ni++)
        acc[mi][ni] = MFMA16(af[mi], bfr[ni], acc[mi][ni]);
  }

#pragma unroll
  for (int mi = 0; mi < 4; mi++) {
#pragma unroll
    for (int r = 0; r < 4; r++) {
      const int m = m0 + wr * 64 + mi * 16 + quad * 4 + r;
#pragma unroll
      for (int ni = 0; ni < 4; ni++) {
        const int n = n0 + wc * 64 + ni * 16 + l15;
        float v = acc[mi][ni][r];
        const size_t idx = coff + (size_t)m * ldc + n;
        if (EPI == 1) {
          v += fl ? ((const float*)biasv)[n] : (float)((const bf16*)biasv)[n];
          if (fl) ((float*)Cv)[idx] = v;
          else    ((bf16*)Cv)[idx] = (bf16)v;
        } else {
          ((bf16*)Cv)[idx] = (bf16)v;
        }
      }
    }
  }
}

// -------------------- flash attention (single batch, canonical bf16) ---------
// grid: (T/64, H), block 256. qkv is [T, 3C]; head h: Q cols [h*64,h*64+64),
// K at +1024, V at +2048. O overwrites the Q columns in-place.
__global__ __launch_bounds__(256) void attn_k(bf16* __restrict__ qkv) {
  __shared__ __align__(16) bf16 sQ[64 * LDSS];
  __shared__ __align__(16) bf16 sK[64 * LDSS];
  __shared__ __align__(16) bf16 sVt[64 * LDSS];   // [dim][key]
  __shared__ __align__(16) bf16 sP[4][16 * LDSS]; // per-wave P tile

  const int tid = threadIdx.x;
  const int lane = tid & 63, wave = tid >> 6;
  const int quad = lane >> 4, l15 = lane & 15;
  const int q0 = blockIdx.x * 64;
  const int h = blockIdx.y;
  bf16* base = qkv + h * DD;
  const bf16* Qp = base;
  const bf16* Kp = base + CC;
  const bf16* Vp = base + 2 * CC;

  const int srow = tid >> 3;          // 0..31
  const int scol = (tid & 7) * 8;     // 0..56

#pragma unroll
  for (int p = 0; p < 2; p++) {
    const int r = p * 32 + srow;
    bf16x8 v = *(const bf16x8*)(Qp + (size_t)(q0 + r) * N_QKV + scol);
    store_lds8(sQ + r * LDSS + scol, v);
  }
  __syncthreads();

  bf16x8 aq[2];
  aq[0] = load_lds8(sQ + (wave * 16 + l15) * LDSS + quad * 8);
  aq[1] = load_lds8(sQ + (wave * 16 + l15) * LDSS + 32 + quad * 8);

  float mrun[4], lrun[4];
  f32x4 Oacc[4];
#pragma unroll
  for (int r = 0; r < 4; r++) { mrun[r] = -1e30f; lrun[r] = 0.f; }
#pragma unroll
  for (int nt = 0; nt < 4; nt++) {
    f32x4 z = {0.f, 0.f, 0.f, 0.f};
    Oacc[nt] = z;
  }

  const float scale = 0.125f;
  const int qrow_base = q0 + wave * 16 + quad * 4;

  for (int j0 = 0; j0 <= q0; j0 += 64) {
    __syncthreads();
#pragma unroll
    for (int p = 0; p < 2; p++) {
      const int r = p * 32 + srow;
      bf16x8 kv = *(const bf16x8*)(Kp + (size_t)(j0 + r) * N_QKV + scol);
      store_lds8(sK + r * LDSS + scol, kv);
      bf16x8 vv = *(const bf16x8*)(Vp + (size_t)(j0 + r) * N_QKV + scol);
#pragma unroll
      for (int i = 0; i < 8; i++)
        sVt[(scol + i) * LDSS + r] = vv[i];
    }
    __syncthreads();

    f32x4 S[4];
#pragma unroll
    for (int nt = 0; nt < 4; nt++) {
      f32x4 z = {0.f, 0.f, 0.f, 0.f};
      S[nt] = z;
      bf16x8 bk0 = load_lds8(sK + (nt * 16 + l15) * LDSS + quad * 8);
      bf16x8 bk1 = load_lds8(sK + (nt * 16 + l15) * LDSS + 32 + quad * 8);
      S[nt] = MFMA16(aq[0], bk0, S[nt]);
      S[nt] = MFMA16(aq[1], bk1, S[nt]);
    }

    float sc[4][4];
    float mx[4];
#pragma unroll
    for (int r = 0; r < 4; r++) mx[r] = -1e30f;
#pragma unroll
    for (int nt = 0; nt < 4; nt++) {
      const int kcol = j0 + nt * 16 + l15;
#pragma unroll
      for (int r = 0; r < 4; r++) {
        float v = S[nt][r] * scale;
        if (kcol > qrow_base + r) v = -1e30f;
        sc[nt][r] = v;
        mx[r] = fmaxf(mx[r], v);
      }
    }
    float alpha[4], rs[4];
#pragma unroll
    for (int r = 0; r < 4; r++) {
      mx[r] = red16_max(mx[r]);
      const float mnew = fmaxf(mrun[r], mx[r]);
      alpha[r] = __expf(mrun[r] - mnew);
      mrun[r] = mnew;
      rs[r] = 0.f;
    }
#pragma unroll
    for (int nt = 0; nt < 4; nt++)
#pragma unroll
      for (int r = 0; r < 4; r++) {
        const float p = __expf(sc[nt][r] - mrun[r]);
        sc[nt][r] = p;
        rs[r] += p;
      }
#pragma unroll
    for (int r = 0; r < 4; r++) lrun[r] = lrun[r] * alpha[r] + red16_sum(rs[r]);

#pragma unroll
    for (int nt = 0; nt < 4; nt++)
#pragma unroll
      for (int r = 0; r < 4; r++)
        sP[wave][(quad * 4 + r) * LDSS + nt * 16 + l15] = (bf16)sc[nt][r];
#pragma unroll
    for (int nt = 0; nt < 4; nt++)
#pragma unroll
      for (int r = 0; r < 4; r++) Oacc[nt][r] *= alpha[r];
    __syncthreads();

    bf16x8 ap0 = load_lds8(sP[wave] + l15 * LDSS + quad * 8);
    bf16x8 ap1 = load_lds8(sP[wave] + l15 * LDSS + 32 + quad * 8);
#pragma unroll
    for (int nt = 0; nt < 4; nt++) {
      bf16x8 bv0 = load_lds8(sVt + (nt * 16 + l15) * LDSS + quad * 8);
      bf16x8 bv1 = load_lds8(sVt + (nt * 16 + l15) * LDSS + 32 + quad * 8);
      Oacc[nt] = MFMA16(ap0, bv0, Oacc[nt]);
      Oacc[nt] = MFMA16(ap1, bv1, Oacc[nt]);
    }
  }

#pragma unroll
  for (int r = 0; r < 4; r++) {
    const float invl = 1.0f / lrun[r];
    const int t = q0 + wave * 16 + quad * 4 + r;
#pragma unroll
    for (int nt = 0; nt < 4; nt++) {
      base[(size_t)t * N_QKV + nt * 16 + l15] = (bf16)(Oacc[nt][r] * invl);
    }
  }
}

// -------------------- launch --------------------
// ws: [flag int | qkvb 2048x3072 bf16] = 12.6 MB. Inputs may be fp32 or bf16;
// sniff_k detects at runtime, GEMMs branch per-load, internal pipeline is bf16.
extern "C" void kernel_launch(void* const* d_in, const int* in_sizes, int n_in,
                              void* d_out, int out_size, void* d_ws, size_t ws_size,
                              hipStream_t stream) {
  const void* x = d_in[0];       // [8192,1024] fp32 or bf16
  const void* w_qkv = d_in[1];   // [1024,3072]
  const void* w_out = d_in[2];   // [1024,1024]
  const void* b_out = d_in[3];   // [1024]

  int* flag = (int*)d_ws;
  bf16* qkvb = (bf16*)((char*)d_ws + 256);   // [2048,3072]

  sniff_k<<<1, 256, 0, stream>>>((const unsigned short*)x, flag);

  for (int b = 0; b < BB; b++) {
    const size_t xoff = (size_t)b * TT * CC;

    // qkv_b = x_b @ w_qkv  -> canonical bf16 [2048,3072]
    gemm_nt<0, true, true><<<dim3(TT / 128, N_QKV / 128), 256, 0, stream>>>(
        x, w_qkv, nullptr, qkvb, flag, xoff, 0, TT, N_QKV, CC, CC, N_QKV);

    // attention; O overwrites Q columns of qkv_b
    attn_k<<<dim3(TT / 64, HH), 256, 0, stream>>>(qkvb);

    // out_b = O @ w_out + b_out (A = qkv_b cols 0..1023, lda=3072)
    gemm_nt<1, false, true><<<dim3(TT / 128, CC / 128), 256, 0, stream>>>(
        qkvb, w_out, b_out, d_out, flag, 0, xoff, TT, CC, CC, N_QKV, CC);
  }
}

// Round 5
// 532.516 us; speedup vs baseline: 1.8866x; 1.8866x over previous
//
#include <hip/hip_runtime.h>

typedef __bf16 bf16;
typedef __bf16 bf16x4 __attribute__((ext_vector_type(4)));
typedef __bf16 bf16x8 __attribute__((ext_vector_type(8)));
typedef float  f32x4  __attribute__((ext_vector_type(4)));

#define MFMA16(A_, B_, C_) __builtin_amdgcn_mfma_f32_16x16x32_bf16((A_), (B_), (C_), 0, 0, 0)

// ---- constants ----
#define BB 4
#define TT 2048
#define CC 1024
#define HH 16
#define DD 64
#define MM (BB * TT)         // 8192
#define N_QKV (3 * CC)       // 3072
#define LDSS 68              // padded LDS row stride for attention tiles
#define BSTRIDE 36           // tier-C sB row stride

static __device__ __forceinline__ void store_lds8(bf16* p, bf16x8 v) {
  bf16x4 lo, hi;
#pragma unroll
  for (int i = 0; i < 4; i++) { lo[i] = v[i]; hi[i] = v[i + 4]; }
  *(bf16x4*)p = lo;
  *(bf16x4*)(p + 4) = hi;
}

static __device__ __forceinline__ bf16x8 load_lds8(const bf16* p) {
  bf16x4 lo = *(const bf16x4*)p;
  bf16x4 hi = *(const bf16x4*)(p + 4);
  bf16x8 v;
#pragma unroll
  for (int i = 0; i < 4; i++) { v[i] = lo[i]; v[i + 4] = hi[i]; }
  return v;
}

static __device__ __forceinline__ float red16_max(float v) {
  v = fmaxf(v, __shfl_xor(v, 1, 64));
  v = fmaxf(v, __shfl_xor(v, 2, 64));
  v = fmaxf(v, __shfl_xor(v, 4, 64));
  v = fmaxf(v, __shfl_xor(v, 8, 64));
  return v;
}
static __device__ __forceinline__ float red16_sum(float v) {
  v += __shfl_xor(v, 1, 64);
  v += __shfl_xor(v, 2, 64);
  v += __shfl_xor(v, 4, 64);
  v += __shfl_xor(v, 8, 64);
  return v;
}

// -------------------- dtype sniff --------------------
// fp32 inputs: uint16 low halves ~uniform -> exp=0xFF patterns occur.
// Genuine bf16 normal data never has exp=0xFF.  1 = fp32 world, 0 = bf16.
__global__ __launch_bounds__(256) void sniff_k(const unsigned short* __restrict__ u,
                                               int* __restrict__ flag) {
  __shared__ int s;
  if (threadIdx.x == 0) s = 0;
  __syncthreads();
  int c = 0;
  for (int i = threadIdx.x; i < 65536; i += 256)
    if ((u[i] & 0x7F80u) == 0x7F80u) c = 1;
  if (c) atomicOr(&s, 1);
  __syncthreads();
  if (threadIdx.x == 0) *flag = s;
}

// ------------- transpose + convert-to-bf16: out[c*R+r] = (bf16)in[r*C+c] -----
__global__ __launch_bounds__(256) void transpose_k(const void* __restrict__ in,
                                                   bf16* __restrict__ out,
                                                   int R, int C,
                                                   const int* __restrict__ flag) {
  __shared__ bf16 tile[32][33];
  const int fl = *flag;
  const int c0 = blockIdx.x * 32, r0 = blockIdx.y * 32;
  const int tx = threadIdx.x & 31, ty = threadIdx.x >> 5;
#pragma unroll
  for (int i = ty; i < 32; i += 8) {
    const size_t idx = (size_t)(r0 + i) * C + c0 + tx;
    tile[i][tx] = fl ? (bf16)((const float*)in)[idx] : ((const bf16*)in)[idx];
  }
  __syncthreads();
#pragma unroll
  for (int i = ty; i < 32; i += 8)
    out[(size_t)(c0 + i) * R + r0 + tx] = tile[tx][i];
}

// ----- GEMM (B pre-transposed): C = A[M,K](lda) @ Bt[N,K]^T [+bias] ----------
// AF: A may be fp32 (branch on *flag). Bt always bf16.
// EPI=0: bf16 store. EPI=1: +bias, store fp32/bf16 per flag.
template <int EPI, bool AF>
__global__ __launch_bounds__(256) void gemm_bt(const void* __restrict__ Av,
                                               const bf16* __restrict__ Bt,
                                               const void* __restrict__ biasv,
                                               void* __restrict__ Cv,
                                               const int* __restrict__ flag,
                                               size_t aoff, size_t coff,
                                               int M, int N, int K,
                                               int lda, int ldc) {
  const int fl = *flag;
  const bool af32 = AF && (fl != 0);
  __shared__ __align__(16) bf16 sA[128 * 32];
  __shared__ __align__(16) bf16 sB[128 * 32];
  const int tid = threadIdx.x;
  const int lane = tid & 63, wave = tid >> 6;
  const int quad = lane >> 4, l15 = lane & 15;
  const int wr = wave >> 1, wc = wave & 1;
  const int m0 = blockIdx.x * 128, n0 = blockIdx.y * 128;
  const int srow = tid >> 2;          // 0..63
  const int scol = (tid & 3) * 8;     // 0,8,16,24

  f32x4 acc[4][4];
#pragma unroll
  for (int i = 0; i < 4; i++)
#pragma unroll
    for (int j = 0; j < 4; j++) {
      f32x4 z = {0.f, 0.f, 0.f, 0.f};
      acc[i][j] = z;
    }

  const size_t abase0 = aoff + (size_t)(m0 + srow) * lda + scol;
  const size_t abase1 = abase0 + (size_t)64 * lda;
  const bf16* Bg0 = Bt + (size_t)(n0 + srow) * K + scol;
  const bf16* Bg1 = Bg0 + (size_t)64 * K;

  for (int k0 = 0; k0 < K; k0 += 32) {
    bf16x8 a0, a1;
    if (af32) {
      const float* Af = (const float*)Av;
      f32x4 p00 = *(const f32x4*)(Af + abase0 + k0);
      f32x4 p01 = *(const f32x4*)(Af + abase0 + k0 + 4);
      f32x4 p10 = *(const f32x4*)(Af + abase1 + k0);
      f32x4 p11 = *(const f32x4*)(Af + abase1 + k0 + 4);
#pragma unroll
      for (int i = 0; i < 4; i++) {
        a0[i] = (bf16)p00[i]; a0[i + 4] = (bf16)p01[i];
        a1[i] = (bf16)p10[i]; a1[i + 4] = (bf16)p11[i];
      }
    } else {
      const bf16* Ab = (const bf16*)Av;
      a0 = *(const bf16x8*)(Ab + abase0 + k0);
      a1 = *(const bf16x8*)(Ab + abase1 + k0);
    }
    bf16x8 b0 = *(const bf16x8*)(Bg0 + k0);
    bf16x8 b1 = *(const bf16x8*)(Bg1 + k0);
    __syncthreads();
    *(bf16x8*)(sA + srow * 32 + scol) = a0;
    *(bf16x8*)(sA + (64 + srow) * 32 + scol) = a1;
    *(bf16x8*)(sB + srow * 32 + scol) = b0;
    *(bf16x8*)(sB + (64 + srow) * 32 + scol) = b1;
    __syncthreads();

    bf16x8 af[4], bfr[4];
#pragma unroll
    for (int mi = 0; mi < 4; mi++)
      af[mi] = *(const bf16x8*)(sA + (wr * 64 + mi * 16 + l15) * 32 + quad * 8);
#pragma unroll
    for (int ni = 0; ni < 4; ni++)
      bfr[ni] = *(const bf16x8*)(sB + (wc * 64 + ni * 16 + l15) * 32 + quad * 8);
#pragma unroll
    for (int mi = 0; mi < 4; mi++)
#pragma unroll
      for (int ni = 0; ni < 4; ni++)
        acc[mi][ni] = MFMA16(af[mi], bfr[ni], acc[mi][ni]);
  }

#pragma unroll
  for (int mi = 0; mi < 4; mi++) {
#pragma unroll
    for (int r = 0; r < 4; r++) {
      const int m = m0 + wr * 64 + mi * 16 + quad * 4 + r;
#pragma unroll
      for (int ni = 0; ni < 4; ni++) {
        const int n = n0 + wc * 64 + ni * 16 + l15;
        float v = acc[mi][ni][r];
        const size_t idx = coff + (size_t)m * ldc + n;
        if (EPI == 1) {
          v += fl ? ((const float*)biasv)[n] : (float)((const bf16*)biasv)[n];
          if (fl) ((float*)Cv)[idx] = v;
          else    ((bf16*)Cv)[idx] = (bf16)v;
        } else {
          ((bf16*)Cv)[idx] = (bf16)v;
        }
      }
    }
  }
}

// ----- tier-C GEMM (W row-major, in-kernel transpose staging; known-correct) -
template <int EPI, bool AF, bool WF>
__global__ __launch_bounds__(256) void gemm_nt(const void* __restrict__ Av,
                                               const void* __restrict__ Wv,
                                               const void* __restrict__ biasv,
                                               void* __restrict__ Cv,
                                               const int* __restrict__ flag,
                                               size_t aoff, size_t coff,
                                               int M, int N, int K,
                                               int lda, int ldc) {
  const int fl = *flag;
  const bool af32 = AF && (fl != 0);
  const bool wf32 = WF && (fl != 0);
  __shared__ __align__(16) bf16 sA[128 * 32];
  __shared__ __align__(16) bf16 sB[128 * BSTRIDE];
  const int tid = threadIdx.x;
  const int lane = tid & 63, wave = tid >> 6;
  const int quad = lane >> 4, l15 = lane & 15;
  const int wr = wave >> 1, wc = wave & 1;
  const int m0 = blockIdx.x * 128, n0 = blockIdx.y * 128;
  const int arow = tid >> 2, acol = (tid & 3) * 8;
  const int wk = tid >> 3, wn = (tid & 7) * 16;

  f32x4 acc[4][4];
#pragma unroll
  for (int i = 0; i < 4; i++)
#pragma unroll
    for (int j = 0; j < 4; j++) {
      f32x4 z = {0.f, 0.f, 0.f, 0.f};
      acc[i][j] = z;
    }

  const size_t abase0 = aoff + (size_t)(m0 + arow) * lda + acol;
  const size_t abase1 = abase0 + (size_t)64 * lda;

  for (int k0 = 0; k0 < K; k0 += 32) {
    bf16x8 a0, a1;
    if (af32) {
      const float* Af = (const float*)Av;
      f32x4 p00 = *(const f32x4*)(Af + abase0 + k0);
      f32x4 p01 = *(const f32x4*)(Af + abase0 + k0 + 4);
      f32x4 p10 = *(const f32x4*)(Af + abase1 + k0);
      f32x4 p11 = *(const f32x4*)(Af + abase1 + k0 + 4);
#pragma unroll
      for (int i = 0; i < 4; i++) {
        a0[i] = (bf16)p00[i]; a0[i + 4] = (bf16)p01[i];
        a1[i] = (bf16)p10[i]; a1[i + 4] = (bf16)p11[i];
      }
    } else {
      const bf16* Ab = (const bf16*)Av;
      a0 = *(const bf16x8*)(Ab + abase0 + k0);
      a1 = *(const bf16x8*)(Ab + abase1 + k0);
    }
    bf16 wreg[16];
    const size_t wbase = (size_t)(k0 + wk) * N + n0 + wn;
    if (wf32) {
      const float* Wf = (const float*)Wv;
      f32x4 q0 = *(const f32x4*)(Wf + wbase);
      f32x4 q1 = *(const f32x4*)(Wf + wbase + 4);
      f32x4 q2 = *(const f32x4*)(Wf + wbase + 8);
      f32x4 q3 = *(const f32x4*)(Wf + wbase + 12);
#pragma unroll
      for (int i = 0; i < 4; i++) {
        wreg[i] = (bf16)q0[i];      wreg[4 + i] = (bf16)q1[i];
        wreg[8 + i] = (bf16)q2[i];  wreg[12 + i] = (bf16)q3[i];
      }
    } else {
      const bf16* Wb = (const bf16*)Wv;
      bf16x8 w0 = *(const bf16x8*)(Wb + wbase);
      bf16x8 w1 = *(const bf16x8*)(Wb + wbase + 8);
#pragma unroll
      for (int i = 0; i < 8; i++) { wreg[i] = w0[i]; wreg[8 + i] = w1[i]; }
    }
    __syncthreads();
    *(bf16x8*)(sA + arow * 32 + acol) = a0;
    *(bf16x8*)(sA + (64 + arow) * 32 + acol) = a1;
#pragma unroll
    for (int i = 0; i < 16; i++)
      sB[(wn + i) * BSTRIDE + wk] = wreg[i];
    __syncthreads();

    bf16x8 af[4], bfr[4];
#pragma unroll
    for (int mi = 0; mi < 4; mi++)
      af[mi] = *(const bf16x8*)(sA + (wr * 64 + mi * 16 + l15) * 32 + quad * 8);
#pragma unroll
    for (int ni = 0; ni < 4; ni++)
      bfr[ni] = load_lds8(sB + (wc * 64 + ni * 16 + l15) * BSTRIDE + quad * 8);
#pragma unroll
    for (int mi = 0; mi < 4; mi++)
#pragma unroll
      for (int ni = 0; ni < 4; ni++)
        acc[mi][ni] = MFMA16(af[mi], bfr[ni], acc[mi][ni]);
  }

#pragma unroll
  for (int mi = 0; mi < 4; mi++) {
#pragma unroll
    for (int r = 0; r < 4; r++) {
      const int m = m0 + wr * 64 + mi * 16 + quad * 4 + r;
#pragma unroll
      for (int ni = 0; ni < 4; ni++) {
        const int n = n0 + wc * 64 + ni * 16 + l15;
        float v = acc[mi][ni][r];
        const size_t idx = coff + (size_t)m * ldc + n;
        if (EPI == 1) {
          v += fl ? ((const float*)biasv)[n] : (float)((const bf16*)biasv)[n];
          if (fl) ((float*)Cv)[idx] = v;
          else    ((bf16*)Cv)[idx] = (bf16)v;
        } else {
          ((bf16*)Cv)[idx] = (bf16)v;
        }
      }
    }
  }
}

// -------------------- flash attention --------------------
// grid: (T/64, nbh), block 256. qkv is [nb*T, 3C]; bh -> b=bh>>4, h=bh&15.
// O overwrites the Q columns in-place. P-tile aliases sQ (sQ dead after aq).
__global__ __launch_bounds__(256) void attn_k(bf16* __restrict__ qkv) {
  __shared__ __align__(16) bf16 sQ[64 * LDSS];     // later reused as P tiles
  __shared__ __align__(16) bf16 sK[64 * LDSS];
  __shared__ __align__(16) bf16 sVt[64 * LDSS];    // [dim][key]

  const int tid = threadIdx.x;
  const int lane = tid & 63, wave = tid >> 6;
  const int quad = lane >> 4, l15 = lane & 15;
  const int q0 = blockIdx.x * 64;
  const int bh = blockIdx.y;
  bf16* base = qkv + (size_t)(bh >> 4) * TT * N_QKV + (bh & 15) * DD;
  const bf16* Qp = base;
  const bf16* Kp = base + CC;
  const bf16* Vp = base + 2 * CC;
  bf16* sP = sQ + wave * 16 * LDSS;   // per-wave 16x64 P tile, aliases sQ

  const int srow = tid >> 3;          // 0..31
  const int scol = (tid & 7) * 8;     // 0..56

#pragma unroll
  for (int p = 0; p < 2; p++) {
    const int r = p * 32 + srow;
    bf16x8 v = *(const bf16x8*)(Qp + (size_t)(q0 + r) * N_QKV + scol);
    store_lds8(sQ + r * LDSS + scol, v);
  }
  __syncthreads();

  bf16x8 aq[2];
  aq[0] = load_lds8(sQ + (wave * 16 + l15) * LDSS + quad * 8);
  aq[1] = load_lds8(sQ + (wave * 16 + l15) * LDSS + 32 + quad * 8);

  float mrun[4], lrun[4];
  f32x4 Oacc[4];
#pragma unroll
  for (int r = 0; r < 4; r++) { mrun[r] = -1e30f; lrun[r] = 0.f; }
#pragma unroll
  for (int nt = 0; nt < 4; nt++) {
    f32x4 z = {0.f, 0.f, 0.f, 0.f};
    Oacc[nt] = z;
  }

  const float scale = 0.125f;
  const int qrow_base = q0 + wave * 16 + quad * 4;

  for (int j0 = 0; j0 <= q0; j0 += 64) {
    __syncthreads();  // prior sK/sVt/sP reads drained (incl. aq on iter 0)
#pragma unroll
    for (int p = 0; p < 2; p++) {
      const int r = p * 32 + srow;
      bf16x8 kv = *(const bf16x8*)(Kp + (size_t)(j0 + r) * N_QKV + scol);
      store_lds8(sK + r * LDSS + scol, kv);
      bf16x8 vv = *(const bf16x8*)(Vp + (size_t)(j0 + r) * N_QKV + scol);
#pragma unroll
      for (int i = 0; i < 8; i++)
        sVt[(scol + i) * LDSS + r] = vv[i];
    }
    __syncthreads();

    f32x4 S[4];
#pragma unroll
    for (int nt = 0; nt < 4; nt++) {
      f32x4 z = {0.f, 0.f, 0.f, 0.f};
      S[nt] = z;
      bf16x8 bk0 = load_lds8(sK + (nt * 16 + l15) * LDSS + quad * 8);
      bf16x8 bk1 = load_lds8(sK + (nt * 16 + l15) * LDSS + 32 + quad * 8);
      S[nt] = MFMA16(aq[0], bk0, S[nt]);
      S[nt] = MFMA16(aq[1], bk1, S[nt]);
    }

    float sc[4][4];
    float mx[4];
#pragma unroll
    for (int r = 0; r < 4; r++) mx[r] = -1e30f;
#pragma unroll
    for (int nt = 0; nt < 4; nt++) {
      const int kcol = j0 + nt * 16 + l15;
#pragma unroll
      for (int r = 0; r < 4; r++) {
        float v = S[nt][r] * scale;
        if (kcol > qrow_base + r) v = -1e30f;
        sc[nt][r] = v;
        mx[r] = fmaxf(mx[r], v);
      }
    }
    float alpha[4], rs[4];
#pragma unroll
    for (int r = 0; r < 4; r++) {
      mx[r] = red16_max(mx[r]);
      const float mnew = fmaxf(mrun[r], mx[r]);
      alpha[r] = __expf(mrun[r] - mnew);
      mrun[r] = mnew;
      rs[r] = 0.f;
    }
#pragma unroll
    for (int nt = 0; nt < 4; nt++)
#pragma unroll
      for (int r = 0; r < 4; r++) {
        const float p = __expf(sc[nt][r] - mrun[r]);
        sc[nt][r] = p;
        rs[r] += p;
      }
#pragma unroll
    for (int r = 0; r < 4; r++) lrun[r] = lrun[r] * alpha[r] + red16_sum(rs[r]);

#pragma unroll
    for (int nt = 0; nt < 4; nt++)
#pragma unroll
      for (int r = 0; r < 4; r++)
        sP[(quad * 4 + r) * LDSS + nt * 16 + l15] = (bf16)sc[nt][r];
#pragma unroll
    for (int nt = 0; nt < 4; nt++)
#pragma unroll
      for (int r = 0; r < 4; r++) Oacc[nt][r] *= alpha[r];
    __syncthreads();

    bf16x8 ap0 = load_lds8(sP + l15 * LDSS + quad * 8);
    bf16x8 ap1 = load_lds8(sP + l15 * LDSS + 32 + quad * 8);
#pragma unroll
    for (int nt = 0; nt < 4; nt++) {
      bf16x8 bv0 = load_lds8(sVt + (nt * 16 + l15) * LDSS + quad * 8);
      bf16x8 bv1 = load_lds8(sVt + (nt * 16 + l15) * LDSS + 32 + quad * 8);
      Oacc[nt] = MFMA16(ap0, bv0, Oacc[nt]);
      Oacc[nt] = MFMA16(ap1, bv1, Oacc[nt]);
    }
  }

#pragma unroll
  for (int r = 0; r < 4; r++) {
    const float invl = 1.0f / lrun[r];
    const int t = q0 + wave * 16 + quad * 4 + r;
#pragma unroll
    for (int nt = 0; nt < 4; nt++) {
      base[(size_t)t * N_QKV + nt * 16 + l15] = (bf16)(Oacc[nt][r] * invl);
    }
  }
}

// -------------------- launch --------------------
extern "C" void kernel_launch(void* const* d_in, const int* in_sizes, int n_in,
                              void* d_out, int out_size, void* d_ws, size_t ws_size,
                              hipStream_t stream) {
  const void* x = d_in[0];       // [8192,1024] fp32 or bf16
  const void* w_qkv = d_in[1];   // [1024,3072]
  const void* w_out = d_in[2];   // [1024,1024]
  const void* b_out = d_in[3];   // [1024]

  int* flag = (int*)d_ws;
  char* p = (char*)d_ws + 256;
  bf16* wqkvT = (bf16*)p;                          // [3072,1024]  6 MB
  bf16* woutT = wqkvT + (size_t)N_QKV * CC;        // [1024,1024]  2 MB
  bf16* qkv = woutT + (size_t)CC * CC;             // fused: [8192,3072] 48 MB

  const size_t wT_bytes = ((size_t)N_QKV * CC + (size_t)CC * CC) * 2;
  const size_t need_fused = 256 + wT_bytes + (size_t)MM * N_QKV * 2;
  const size_t need_tierB = 256 + wT_bytes + (size_t)TT * N_QKV * 2;

  sniff_k<<<1, 256, 0, stream>>>((const unsigned short*)x, flag);

  if (ws_size >= need_fused) {
    // ---- Tier A: fully batched ----
    transpose_k<<<dim3(N_QKV / 32, CC / 32), 256, 0, stream>>>(w_qkv, wqkvT, CC, N_QKV, flag);
    transpose_k<<<dim3(CC / 32, CC / 32), 256, 0, stream>>>(w_out, woutT, CC, CC, flag);

    gemm_bt<0, true><<<dim3(MM / 128, N_QKV / 128), 256, 0, stream>>>(
        x, wqkvT, nullptr, qkv, flag, 0, 0, MM, N_QKV, CC, CC, N_QKV);

    attn_k<<<dim3(TT / 64, BB * HH), 256, 0, stream>>>(qkv);

    gemm_bt<1, false><<<dim3(MM / 128, CC / 128), 256, 0, stream>>>(
        qkv, woutT, b_out, d_out, flag, 0, 0, MM, CC, CC, N_QKV, CC);
  } else if (ws_size >= need_tierB) {
    // ---- Tier B: per-batch, pre-transposed weights ----
    transpose_k<<<dim3(N_QKV / 32, CC / 32), 256, 0, stream>>>(w_qkv, wqkvT, CC, N_QKV, flag);
    transpose_k<<<dim3(CC / 32, CC / 32), 256, 0, stream>>>(w_out, woutT, CC, CC, flag);
    for (int b = 0; b < BB; b++) {
      const size_t xoff = (size_t)b * TT * CC;
      gemm_bt<0, true><<<dim3(TT / 128, N_QKV / 128), 256, 0, stream>>>(
          x, wqkvT, nullptr, qkv, flag, xoff, 0, TT, N_QKV, CC, CC, N_QKV);
      attn_k<<<dim3(TT / 64, HH), 256, 0, stream>>>(qkv);
      gemm_bt<1, false><<<dim3(TT / 128, CC / 128), 256, 0, stream>>>(
          qkv, woutT, b_out, d_out, flag, 0, xoff, TT, CC, CC, N_QKV, CC);
    }
  } else {
    // ---- Tier C: round-4 proven path (12.6 MB) ----
    bf16* qkvb = (bf16*)p;
    for (int b = 0; b < BB; b++) {
      const size_t xoff = (size_t)b * TT * CC;
      gemm_nt<0, true, true><<<dim3(TT / 128, N_QKV / 128), 256, 0, stream>>>(
          x, w_qkv, nullptr, qkvb, flag, xoff, 0, TT, N_QKV, CC, CC, N_QKV);
      attn_k<<<dim3(TT / 64, HH), 256, 0, stream>>>(qkvb);
      gemm_nt<1, false, true><<<dim3(TT / 128, CC / 128), 256, 0, stream>>>(
          qkvb, w_out, b_out, d_out, flag, 0, xoff, TT, CC, CC, N_QKV, CC);
    }
  }
}

// Round 6
// 483.644 us; speedup vs baseline: 2.0772x; 1.1010x over previous
//
#include <hip/hip_runtime.h>

typedef __bf16 bf16;
typedef __bf16 bf16x4 __attribute__((ext_vector_type(4)));
typedef __bf16 bf16x8 __attribute__((ext_vector_type(8)));
typedef float  f32x4  __attribute__((ext_vector_type(4)));

#define MFMA16(A_, B_, C_) __builtin_amdgcn_mfma_f32_16x16x32_bf16((A_), (B_), (C_), 0, 0, 0)

// ---- constants ----
#define BB 4
#define TT 2048
#define CC 1024
#define HH 16
#define DD 64
#define MM (BB * TT)         // 8192
#define N_QKV (3 * CC)       // 3072
#define LDSS 68              // padded LDS row stride for attention tiles
#define BSTRIDE 36           // tier-C sB row stride

static __device__ __forceinline__ void store_lds8(bf16* p, bf16x8 v) {
  bf16x4 lo, hi;
#pragma unroll
  for (int i = 0; i < 4; i++) { lo[i] = v[i]; hi[i] = v[i + 4]; }
  *(bf16x4*)p = lo;
  *(bf16x4*)(p + 4) = hi;
}

static __device__ __forceinline__ bf16x8 load_lds8(const bf16* p) {
  bf16x4 lo = *(const bf16x4*)p;
  bf16x4 hi = *(const bf16x4*)(p + 4);
  bf16x8 v;
#pragma unroll
  for (int i = 0; i < 4; i++) { v[i] = lo[i]; v[i + 4] = hi[i]; }
  return v;
}

static __device__ __forceinline__ float red16_max(float v) {
  v = fmaxf(v, __shfl_xor(v, 1, 64));
  v = fmaxf(v, __shfl_xor(v, 2, 64));
  v = fmaxf(v, __shfl_xor(v, 4, 64));
  v = fmaxf(v, __shfl_xor(v, 8, 64));
  return v;
}
static __device__ __forceinline__ float red16_sum(float v) {
  v += __shfl_xor(v, 1, 64);
  v += __shfl_xor(v, 2, 64);
  v += __shfl_xor(v, 4, 64);
  v += __shfl_xor(v, 8, 64);
  return v;
}

// -------------------- dtype sniff --------------------
__global__ __launch_bounds__(256) void sniff_k(const unsigned short* __restrict__ u,
                                               int* __restrict__ flag) {
  __shared__ int s;
  if (threadIdx.x == 0) s = 0;
  __syncthreads();
  int c = 0;
  for (int i = threadIdx.x; i < 65536; i += 256)
    if ((u[i] & 0x7F80u) == 0x7F80u) c = 1;
  if (c) atomicOr(&s, 1);
  __syncthreads();
  if (threadIdx.x == 0) *flag = s;   // 1 = fp32 world, 0 = bf16 world
}

// -------------------- x -> bf16 convert (or copy-through) --------------------
__global__ __launch_bounds__(256) void cvt_k(const void* __restrict__ in,
                                             bf16* __restrict__ out,
                                             const int* __restrict__ flag) {
  const int fl = *flag;
  const size_t i = ((size_t)blockIdx.x * 256 + threadIdx.x) * 8;
  if (fl) {
    f32x4 a = *(const f32x4*)((const float*)in + i);
    f32x4 b = *(const f32x4*)((const float*)in + i + 4);
    bf16x8 o;
#pragma unroll
    for (int j = 0; j < 4; j++) { o[j] = (bf16)a[j]; o[4 + j] = (bf16)b[j]; }
    *(bf16x8*)(out + i) = o;
  } else {
    *(bf16x8*)(out + i) = *(const bf16x8*)((const bf16*)in + i);
  }
}

// ------------- transpose + convert-to-bf16: out[c*R+r] = (bf16)in[r*C+c] -----
__global__ __launch_bounds__(256) void transpose_k(const void* __restrict__ in,
                                                   bf16* __restrict__ out,
                                                   int R, int C,
                                                   const int* __restrict__ flag) {
  __shared__ bf16 tile[32][33];
  const int fl = *flag;
  const int c0 = blockIdx.x * 32, r0 = blockIdx.y * 32;
  const int tx = threadIdx.x & 31, ty = threadIdx.x >> 5;
#pragma unroll
  for (int i = ty; i < 32; i += 8) {
    const size_t idx = (size_t)(r0 + i) * C + c0 + tx;
    tile[i][tx] = fl ? (bf16)((const float*)in)[idx] : ((const bf16*)in)[idx];
  }
  __syncthreads();
#pragma unroll
  for (int i = ty; i < 32; i += 8)
    out[(size_t)(c0 + i) * R + r0 + tx] = tile[tx][i];
}

// ----- GEMM (B pre-transposed): C = A[M,K](lda) @ Bt[N,K]^T [+bias] ----------
template <int EPI, bool AF>
__global__ __launch_bounds__(256) void gemm_bt(const void* __restrict__ Av,
                                               const bf16* __restrict__ Bt,
                                               const void* __restrict__ biasv,
                                               void* __restrict__ Cv,
                                               const int* __restrict__ flag,
                                               size_t aoff, size_t coff,
                                               int M, int N, int K,
                                               int lda, int ldc) {
  const int fl = *flag;
  const bool af32 = AF && (fl != 0);
  __shared__ __align__(16) bf16 sA[128 * 32];
  __shared__ __align__(16) bf16 sB[128 * 32];
  const int tid = threadIdx.x;
  const int lane = tid & 63, wave = tid >> 6;
  const int quad = lane >> 4, l15 = lane & 15;
  const int wr = wave >> 1, wc = wave & 1;
  const int m0 = blockIdx.x * 128, n0 = blockIdx.y * 128;
  const int srow = tid >> 2;          // 0..63
  const int scol = (tid & 3) * 8;     // 0,8,16,24

  f32x4 acc[4][4];
#pragma unroll
  for (int i = 0; i < 4; i++)
#pragma unroll
    for (int j = 0; j < 4; j++) {
      f32x4 z = {0.f, 0.f, 0.f, 0.f};
      acc[i][j] = z;
    }

  const size_t abase0 = aoff + (size_t)(m0 + srow) * lda + scol;
  const size_t abase1 = abase0 + (size_t)64 * lda;
  const bf16* Bg0 = Bt + (size_t)(n0 + srow) * K + scol;
  const bf16* Bg1 = Bg0 + (size_t)64 * K;

  for (int k0 = 0; k0 < K; k0 += 32) {
    bf16x8 a0, a1;
    if (af32) {
      const float* Af = (const float*)Av;
      f32x4 p00 = *(const f32x4*)(Af + abase0 + k0);
      f32x4 p01 = *(const f32x4*)(Af + abase0 + k0 + 4);
      f32x4 p10 = *(const f32x4*)(Af + abase1 + k0);
      f32x4 p11 = *(const f32x4*)(Af + abase1 + k0 + 4);
#pragma unroll
      for (int i = 0; i < 4; i++) {
        a0[i] = (bf16)p00[i]; a0[i + 4] = (bf16)p01[i];
        a1[i] = (bf16)p10[i]; a1[i + 4] = (bf16)p11[i];
      }
    } else {
      const bf16* Ab = (const bf16*)Av;
      a0 = *(const bf16x8*)(Ab + abase0 + k0);
      a1 = *(const bf16x8*)(Ab + abase1 + k0);
    }
    bf16x8 b0 = *(const bf16x8*)(Bg0 + k0);
    bf16x8 b1 = *(const bf16x8*)(Bg1 + k0);
    __syncthreads();
    *(bf16x8*)(sA + srow * 32 + scol) = a0;
    *(bf16x8*)(sA + (64 + srow) * 32 + scol) = a1;
    *(bf16x8*)(sB + srow * 32 + scol) = b0;
    *(bf16x8*)(sB + (64 + srow) * 32 + scol) = b1;
    __syncthreads();

    bf16x8 af[4], bfr[4];
#pragma unroll
    for (int mi = 0; mi < 4; mi++)
      af[mi] = *(const bf16x8*)(sA + (wr * 64 + mi * 16 + l15) * 32 + quad * 8);
#pragma unroll
    for (int ni = 0; ni < 4; ni++)
      bfr[ni] = *(const bf16x8*)(sB + (wc * 64 + ni * 16 + l15) * 32 + quad * 8);
#pragma unroll
    for (int mi = 0; mi < 4; mi++)
#pragma unroll
      for (int ni = 0; ni < 4; ni++)
        acc[mi][ni] = MFMA16(af[mi], bfr[ni], acc[mi][ni]);
  }

#pragma unroll
  for (int mi = 0; mi < 4; mi++) {
#pragma unroll
    for (int r = 0; r < 4; r++) {
      const int m = m0 + wr * 64 + mi * 16 + quad * 4 + r;
#pragma unroll
      for (int ni = 0; ni < 4; ni++) {
        const int n = n0 + wc * 64 + ni * 16 + l15;
        float v = acc[mi][ni][r];
        const size_t idx = coff + (size_t)m * ldc + n;
        if (EPI == 1) {
          v += fl ? ((const float*)biasv)[n] : (float)((const bf16*)biasv)[n];
          if (fl) ((float*)Cv)[idx] = v;
          else    ((bf16*)Cv)[idx] = (bf16)v;
        } else {
          ((bf16*)Cv)[idx] = (bf16)v;
        }
      }
    }
  }
}

// ----- tier-C GEMM (W row-major, in-kernel transpose staging) ----------------
template <int EPI, bool AF, bool WF>
__global__ __launch_bounds__(256) void gemm_nt(const void* __restrict__ Av,
                                               const void* __restrict__ Wv,
                                               const void* __restrict__ biasv,
                                               void* __restrict__ Cv,
                                               const int* __restrict__ flag,
                                               size_t aoff, size_t coff,
                                               int M, int N, int K,
                                               int lda, int ldc) {
  const int fl = *flag;
  const bool af32 = AF && (fl != 0);
  const bool wf32 = WF && (fl != 0);
  __shared__ __align__(16) bf16 sA[128 * 32];
  __shared__ __align__(16) bf16 sB[128 * BSTRIDE];
  const int tid = threadIdx.x;
  const int lane = tid & 63, wave = tid >> 6;
  const int quad = lane >> 4, l15 = lane & 15;
  const int wr = wave >> 1, wc = wave & 1;
  const int m0 = blockIdx.x * 128, n0 = blockIdx.y * 128;
  const int arow = tid >> 2, acol = (tid & 3) * 8;
  const int wk = tid >> 3, wn = (tid & 7) * 16;

  f32x4 acc[4][4];
#pragma unroll
  for (int i = 0; i < 4; i++)
#pragma unroll
    for (int j = 0; j < 4; j++) {
      f32x4 z = {0.f, 0.f, 0.f, 0.f};
      acc[i][j] = z;
    }

  const size_t abase0 = aoff + (size_t)(m0 + arow) * lda + acol;
  const size_t abase1 = abase0 + (size_t)64 * lda;

  for (int k0 = 0; k0 < K; k0 += 32) {
    bf16x8 a0, a1;
    if (af32) {
      const float* Af = (const float*)Av;
      f32x4 p00 = *(const f32x4*)(Af + abase0 + k0);
      f32x4 p01 = *(const f32x4*)(Af + abase0 + k0 + 4);
      f32x4 p10 = *(const f32x4*)(Af + abase1 + k0);
      f32x4 p11 = *(const f32x4*)(Af + abase1 + k0 + 4);
#pragma unroll
      for (int i = 0; i < 4; i++) {
        a0[i] = (bf16)p00[i]; a0[i + 4] = (bf16)p01[i];
        a1[i] = (bf16)p10[i]; a1[i + 4] = (bf16)p11[i];
      }
    } else {
      const bf16* Ab = (const bf16*)Av;
      a0 = *(const bf16x8*)(Ab + abase0 + k0);
      a1 = *(const bf16x8*)(Ab + abase1 + k0);
    }
    bf16 wreg[16];
    const size_t wbase = (size_t)(k0 + wk) * N + n0 + wn;
    if (wf32) {
      const float* Wf = (const float*)Wv;
      f32x4 q0 = *(const f32x4*)(Wf + wbase);
      f32x4 q1 = *(const f32x4*)(Wf + wbase + 4);
      f32x4 q2 = *(const f32x4*)(Wf + wbase + 8);
      f32x4 q3 = *(const f32x4*)(Wf + wbase + 12);
#pragma unroll
      for (int i = 0; i < 4; i++) {
        wreg[i] = (bf16)q0[i];      wreg[4 + i] = (bf16)q1[i];
        wreg[8 + i] = (bf16)q2[i];  wreg[12 + i] = (bf16)q3[i];
      }
    } else {
      const bf16* Wb = (const bf16*)Wv;
      bf16x8 w0 = *(const bf16x8*)(Wb + wbase);
      bf16x8 w1 = *(const bf16x8*)(Wb + wbase + 8);
#pragma unroll
      for (int i = 0; i < 8; i++) { wreg[i] = w0[i]; wreg[8 + i] = w1[i]; }
    }
    __syncthreads();
    *(bf16x8*)(sA + arow * 32 + acol) = a0;
    *(bf16x8*)(sA + (64 + arow) * 32 + acol) = a1;
#pragma unroll
    for (int i = 0; i < 16; i++)
      sB[(wn + i) * BSTRIDE + wk] = wreg[i];
    __syncthreads();

    bf16x8 af[4], bfr[4];
#pragma unroll
    for (int mi = 0; mi < 4; mi++)
      af[mi] = *(const bf16x8*)(sA + (wr * 64 + mi * 16 + l15) * 32 + quad * 8);
#pragma unroll
    for (int ni = 0; ni < 4; ni++)
      bfr[ni] = load_lds8(sB + (wc * 64 + ni * 16 + l15) * BSTRIDE + quad * 8);
#pragma unroll
    for (int mi = 0; mi < 4; mi++)
#pragma unroll
      for (int ni = 0; ni < 4; ni++)
        acc[mi][ni] = MFMA16(af[mi], bfr[ni], acc[mi][ni]);
  }

#pragma unroll
  for (int mi = 0; mi < 4; mi++) {
#pragma unroll
    for (int r = 0; r < 4; r++) {
      const int m = m0 + wr * 64 + mi * 16 + quad * 4 + r;
#pragma unroll
      for (int ni = 0; ni < 4; ni++) {
        const int n = n0 + wc * 64 + ni * 16 + l15;
        float v = acc[mi][ni][r];
        const size_t idx = coff + (size_t)m * ldc + n;
        if (EPI == 1) {
          v += fl ? ((const float*)biasv)[n] : (float)((const bf16*)biasv)[n];
          if (fl) ((float*)Cv)[idx] = v;
          else    ((bf16*)Cv)[idx] = (bf16)v;
        } else {
          ((bf16*)Cv)[idx] = (bf16)v;
        }
      }
    }
  }
}

// -------------------- flash attention, 128-row Q tiles --------------------
// grid: (T/128, nb*H), block 256. Wave w owns rows q0+w*32 .. +31 (2 m-frags).
// Prefetch: next tile's K/V global loads issued right after the store barrier,
// overlapping compute. V staged transposed with conflict-free lane mapping.
// P tile is wave-private, aliased onto this wave's sQ rows (no 3rd barrier).
__global__ __launch_bounds__(256) void attn_k(bf16* __restrict__ qkv) {
  __shared__ __align__(16) bf16 sQ[128 * LDSS];
  __shared__ __align__(16) bf16 sK[64 * LDSS];
  __shared__ __align__(16) bf16 sVt[64 * LDSS];   // [dim][key]

  const int tid = threadIdx.x;
  const int lane = tid & 63, wave = tid >> 6;
  const int quad = lane >> 4, l15 = lane & 15;
  const int q0 = blockIdx.x * 128;
  const int bh = blockIdx.y;
  bf16* base = qkv + (size_t)(bh >> 4) * TT * N_QKV + (bh & 15) * DD;
  const bf16* Qp = base;
  const bf16* Kp = base + CC;
  const bf16* Vp = base + 2 * CC;

  const int krow = tid >> 2;          // 0..63
  const int kcol = (tid & 3) * 16;    // 0,16,32,48
  const int vkey = tid & 31;          // 0..31  (consecutive lanes = consecutive keys)
  const int vcol = (tid >> 5) * 8;    // 0..56

  // ---- stage Q: 128 rows x 64 dims ----
#pragma unroll
  for (int p = 0; p < 2; p++) {
    const int r = p * 64 + krow;
    const bf16* src = Qp + (size_t)(q0 + r) * N_QKV + kcol;
    store_lds8(sQ + r * LDSS + kcol, *(const bf16x8*)src);
    store_lds8(sQ + r * LDSS + kcol + 8, *(const bf16x8*)(src + 8));
  }
  __syncthreads();

  bf16x8 aq[2][2];
#pragma unroll
  for (int mi = 0; mi < 2; mi++) {
    const bf16* qp = sQ + (size_t)(wave * 32 + mi * 16 + l15) * LDSS + quad * 8;
    aq[mi][0] = load_lds8(qp);
    aq[mi][1] = load_lds8(qp + 32);
  }

  float mrun[2][4], lrun[2][4];
  f32x4 Oacc[2][4];
#pragma unroll
  for (int mi = 0; mi < 2; mi++)
#pragma unroll
    for (int r = 0; r < 4; r++) { mrun[mi][r] = -1e30f; lrun[mi][r] = 0.f; }
#pragma unroll
  for (int mi = 0; mi < 2; mi++)
#pragma unroll
    for (int nt = 0; nt < 4; nt++) {
      f32x4 z = {0.f, 0.f, 0.f, 0.f};
      Oacc[mi][nt] = z;
    }

  const float scale = 0.125f;
  const int jmax = q0 + 64;           // last j-tile start
  const int wave_row0 = q0 + wave * 32;
  bf16* sP = sQ + (size_t)(wave * 32) * LDSS;   // wave-private P region

  // prefetch tile 0
  bf16x8 kr0, kr1, vr0, vr1;
  {
    const bf16* kp = Kp + (size_t)krow * N_QKV + kcol;
    kr0 = *(const bf16x8*)kp;
    kr1 = *(const bf16x8*)(kp + 8);
    vr0 = *(const bf16x8*)(Vp + (size_t)vkey * N_QKV + vcol);
    vr1 = *(const bf16x8*)(Vp + (size_t)(32 + vkey) * N_QKV + vcol);
  }

  for (int j0 = 0; j0 <= jmax; j0 += 64) {
    __syncthreads();                  // prior tile's sK/sVt reads done
    store_lds8(sK + krow * LDSS + kcol, kr0);
    store_lds8(sK + krow * LDSS + kcol + 8, kr1);
#pragma unroll
    for (int i = 0; i < 8; i++) {
      sVt[(vcol + i) * LDSS + vkey] = vr0[i];
      sVt[(vcol + i) * LDSS + 32 + vkey] = vr1[i];
    }
    __syncthreads();

    if (j0 + 64 <= jmax) {            // prefetch next tile (overlaps compute)
      const bf16* kp = Kp + (size_t)(j0 + 64 + krow) * N_QKV + kcol;
      kr0 = *(const bf16x8*)kp;
      kr1 = *(const bf16x8*)(kp + 8);
      vr0 = *(const bf16x8*)(Vp + (size_t)(j0 + 64 + vkey) * N_QKV + vcol);
      vr1 = *(const bf16x8*)(Vp + (size_t)(j0 + 96 + vkey) * N_QKV + vcol);
    }

    if (j0 <= wave_row0 + 31) {       // skip fully-masked tiles (wave-uniform)
      // ---- S = Q K^T ----
      f32x4 S[2][4];
#pragma unroll
      for (int nt = 0; nt < 4; nt++) {
        const bf16* kp = sK + (size_t)(nt * 16 + l15) * LDSS + quad * 8;
        bf16x8 bk0 = load_lds8(kp);
        bf16x8 bk1 = load_lds8(kp + 32);
#pragma unroll
        for (int mi = 0; mi < 2; mi++) {
          f32x4 acc = {0.f, 0.f, 0.f, 0.f};
          acc = MFMA16(aq[mi][0], bk0, acc);
          acc = MFMA16(aq[mi][1], bk1, acc);
          S[mi][nt] = acc;
        }
      }

      // ---- scale + (boundary-only) causal mask + row max ----
      const bool needmask = (j0 + 63 > wave_row0);
      float mx[2][4];
#pragma unroll
      for (int mi = 0; mi < 2; mi++)
#pragma unroll
        for (int r = 0; r < 4; r++) mx[mi][r] = -1e30f;
#pragma unroll
      for (int mi = 0; mi < 2; mi++) {
#pragma unroll
        for (int nt = 0; nt < 4; nt++) {
          const int kc = j0 + nt * 16 + l15;
#pragma unroll
          for (int r = 0; r < 4; r++) {
            float v = S[mi][nt][r] * scale;
            if (needmask && kc > wave_row0 + mi * 16 + quad * 4 + r) v = -1e30f;
            S[mi][nt][r] = v;
            mx[mi][r] = fmaxf(mx[mi][r], v);
          }
        }
      }
      float alpha[2][4];
#pragma unroll
      for (int mi = 0; mi < 2; mi++)
#pragma unroll
        for (int r = 0; r < 4; r++) {
          const float m = red16_max(mx[mi][r]);
          const float mnew = fmaxf(mrun[mi][r], m);
          alpha[mi][r] = __expf(mrun[mi][r] - mnew);
          mrun[mi][r] = mnew;
        }
      float rs[2][4];
#pragma unroll
      for (int mi = 0; mi < 2; mi++)
#pragma unroll
        for (int r = 0; r < 4; r++) rs[mi][r] = 0.f;
#pragma unroll
      for (int mi = 0; mi < 2; mi++)
#pragma unroll
        for (int nt = 0; nt < 4; nt++)
#pragma unroll
          for (int r = 0; r < 4; r++) {
            const float pexp = __expf(S[mi][nt][r] - mrun[mi][r]);
            S[mi][nt][r] = pexp;
            rs[mi][r] += pexp;
          }
#pragma unroll
      for (int mi = 0; mi < 2; mi++)
#pragma unroll
        for (int r = 0; r < 4; r++)
          lrun[mi][r] = lrun[mi][r] * alpha[mi][r] + red16_sum(rs[mi][r]);

      // ---- P -> wave-private LDS (conflict-free), O rescale ----
#pragma unroll
      for (int mi = 0; mi < 2; mi++)
#pragma unroll
        for (int nt = 0; nt < 4; nt++)
#pragma unroll
          for (int r = 0; r < 4; r++)
            sP[(size_t)(mi * 16 + quad * 4 + r) * LDSS + nt * 16 + l15] =
                (bf16)S[mi][nt][r];
#pragma unroll
      for (int mi = 0; mi < 2; mi++)
#pragma unroll
        for (int nt = 0; nt < 4; nt++)
#pragma unroll
          for (int r = 0; r < 4; r++) Oacc[mi][nt][r] *= alpha[mi][r];

      // ---- O += P V ----
      bf16x8 ap[2][2];
#pragma unroll
      for (int mi = 0; mi < 2; mi++) {
        const bf16* pp = sP + (size_t)(mi * 16 + l15) * LDSS + quad * 8;
        ap[mi][0] = load_lds8(pp);
        ap[mi][1] = load_lds8(pp + 32);
      }
#pragma unroll
      for (int nt = 0; nt < 4; nt++) {
        const bf16* vp = sVt + (size_t)(nt * 16 + l15) * LDSS + quad * 8;
        bf16x8 bv0 = load_lds8(vp);
        bf16x8 bv1 = load_lds8(vp + 32);
#pragma unroll
        for (int mi = 0; mi < 2; mi++) {
          Oacc[mi][nt] = MFMA16(ap[mi][0], bv0, Oacc[mi][nt]);
          Oacc[mi][nt] = MFMA16(ap[mi][1], bv1, Oacc[mi][nt]);
        }
      }
    }
  }

  // ---- epilogue: O / l over the Q columns in-place ----
#pragma unroll
  for (int mi = 0; mi < 2; mi++)
#pragma unroll
    for (int r = 0; r < 4; r++) {
      const float invl = 1.0f / lrun[mi][r];
      const int t = q0 + wave * 32 + mi * 16 + quad * 4 + r;
#pragma unroll
      for (int nt = 0; nt < 4; nt++)
        base[(size_t)t * N_QKV + nt * 16 + l15] = (bf16)(Oacc[mi][nt][r] * invl);
    }
}

// -------------------- launch --------------------
extern "C" void kernel_launch(void* const* d_in, const int* in_sizes, int n_in,
                              void* d_out, int out_size, void* d_ws, size_t ws_size,
                              hipStream_t stream) {
  const void* x = d_in[0];       // [8192,1024] fp32 or bf16
  const void* w_qkv = d_in[1];   // [1024,3072]
  const void* w_out = d_in[2];   // [1024,1024]
  const void* b_out = d_in[3];   // [1024]

  int* flag = (int*)d_ws;
  char* p = (char*)d_ws + 256;
  bf16* wqkvT = (bf16*)p;                          // [3072,1024]  6 MB
  bf16* woutT = wqkvT + (size_t)N_QKV * CC;        // [1024,1024]  2 MB

  const size_t wT_bytes = ((size_t)N_QKV * CC + (size_t)CC * CC) * 2;  // 8 MB
  const size_t xb_bytes = (size_t)MM * CC * 2;                         // 16 MB
  const size_t qkv_bytes = (size_t)MM * N_QKV * 2;                     // 48 MB
  const size_t need_Ap = 256 + wT_bytes + xb_bytes + qkv_bytes;
  const size_t need_A  = 256 + wT_bytes + qkv_bytes;
  const size_t need_B  = 256 + wT_bytes + (size_t)TT * N_QKV * 2;

  sniff_k<<<1, 256, 0, stream>>>((const unsigned short*)x, flag);

  if (ws_size >= need_Ap) {
    // ---- Tier A+: fused, pre-converted bf16 x ----
    bf16* xb = woutT + (size_t)CC * CC;
    bf16* qkv = xb + (size_t)MM * CC;
    cvt_k<<<(MM * CC) / 2048, 256, 0, stream>>>(x, xb, flag);
    transpose_k<<<dim3(N_QKV / 32, CC / 32), 256, 0, stream>>>(w_qkv, wqkvT, CC, N_QKV, flag);
    transpose_k<<<dim3(CC / 32, CC / 32), 256, 0, stream>>>(w_out, woutT, CC, CC, flag);

    gemm_bt<0, false><<<dim3(MM / 128, N_QKV / 128), 256, 0, stream>>>(
        xb, wqkvT, nullptr, qkv, flag, 0, 0, MM, N_QKV, CC, CC, N_QKV);

    attn_k<<<dim3(TT / 128, BB * HH), 256, 0, stream>>>(qkv);

    gemm_bt<1, false><<<dim3(MM / 128, CC / 128), 256, 0, stream>>>(
        qkv, woutT, b_out, d_out, flag, 0, 0, MM, CC, CC, N_QKV, CC);
  } else if (ws_size >= need_A) {
    // ---- Tier A: fused ----
    bf16* qkv = woutT + (size_t)CC * CC;
    transpose_k<<<dim3(N_QKV / 32, CC / 32), 256, 0, stream>>>(w_qkv, wqkvT, CC, N_QKV, flag);
    transpose_k<<<dim3(CC / 32, CC / 32), 256, 0, stream>>>(w_out, woutT, CC, CC, flag);

    gemm_bt<0, true><<<dim3(MM / 128, N_QKV / 128), 256, 0, stream>>>(
        x, wqkvT, nullptr, qkv, flag, 0, 0, MM, N_QKV, CC, CC, N_QKV);

    attn_k<<<dim3(TT / 128, BB * HH), 256, 0, stream>>>(qkv);

    gemm_bt<1, false><<<dim3(MM / 128, CC / 128), 256, 0, stream>>>(
        qkv, woutT, b_out, d_out, flag, 0, 0, MM, CC, CC, N_QKV, CC);
  } else if (ws_size >= need_B) {
    // ---- Tier B: per-batch, pre-transposed weights ----
    bf16* qkv = woutT + (size_t)CC * CC;
    transpose_k<<<dim3(N_QKV / 32, CC / 32), 256, 0, stream>>>(w_qkv, wqkvT, CC, N_QKV, flag);
    transpose_k<<<dim3(CC / 32, CC / 32), 256, 0, stream>>>(w_out, woutT, CC, CC, flag);
    for (int b = 0; b < BB; b++) {
      const size_t xoff = (size_t)b * TT * CC;
      gemm_bt<0, true><<<dim3(TT / 128, N_QKV / 128), 256, 0, stream>>>(
          x, wqkvT, nullptr, qkv, flag, xoff, 0, TT, N_QKV, CC, CC, N_QKV);
      attn_k<<<dim3(TT / 128, HH), 256, 0, stream>>>(qkv);
      gemm_bt<1, false><<<dim3(TT / 128, CC / 128), 256, 0, stream>>>(
          qkv, woutT, b_out, d_out, flag, 0, xoff, TT, CC, CC, N_QKV, CC);
    }
  } else {
    // ---- Tier C: minimal ws ----
    bf16* qkvb = (bf16*)p;
    for (int b = 0; b < BB; b++) {
      const size_t xoff = (size_t)b * TT * CC;
      gemm_nt<0, true, true><<<dim3(TT / 128, N_QKV / 128), 256, 0, stream>>>(
          x, w_qkv, nullptr, qkvb, flag, xoff, 0, TT, N_QKV, CC, CC, N_QKV);
      attn_k<<<dim3(TT / 128, HH), 256, 0, stream>>>(qkvb);
      gemm_nt<1, false, true><<<dim3(TT / 128, CC / 128), 256, 0, stream>>>(
          qkvb, w_out, b_out, d_out, flag, 0, xoff, TT, CC, CC, N_QKV, CC);
    }
  }
}

// Round 7
// 334.712 us; speedup vs baseline: 3.0014x; 1.4450x over previous
//
#include <hip/hip_runtime.h>

typedef __bf16 bf16;
typedef __bf16 bf16x4 __attribute__((ext_vector_type(4)));
typedef __bf16 bf16x8 __attribute__((ext_vector_type(8)));
typedef float  f32x4  __attribute__((ext_vector_type(4)));

#define MFMA16(A_, B_, C_) __builtin_amdgcn_mfma_f32_16x16x32_bf16((A_), (B_), (C_), 0, 0, 0)

// ---- constants ----
#define BB 4
#define TT 2048
#define CC 1024
#define HH 16
#define DD 64
#define MM (BB * TT)         // 8192
#define N_QKV (3 * CC)       // 3072
#define LDSS 68              // padded LDS row stride for attention tiles
#define BSTRIDE 36           // tier-C sB row stride
#define QSCALE 0.125f        // 1/sqrt(D), folded into staged Q

static __device__ __forceinline__ void store_lds8(bf16* p, bf16x8 v) {
  bf16x4 lo, hi;
#pragma unroll
  for (int i = 0; i < 4; i++) { lo[i] = v[i]; hi[i] = v[i + 4]; }
  *(bf16x4*)p = lo;
  *(bf16x4*)(p + 4) = hi;
}

static __device__ __forceinline__ bf16x8 load_lds8(const bf16* p) {
  bf16x4 lo = *(const bf16x4*)p;
  bf16x4 hi = *(const bf16x4*)(p + 4);
  bf16x8 v;
#pragma unroll
  for (int i = 0; i < 4; i++) { v[i] = lo[i]; v[i + 4] = hi[i]; }
  return v;
}

// -------------------- dtype sniff --------------------
__global__ __launch_bounds__(256) void sniff_k(const unsigned short* __restrict__ u,
                                               int* __restrict__ flag) {
  __shared__ int s;
  if (threadIdx.x == 0) s = 0;
  __syncthreads();
  int c = 0;
  for (int i = threadIdx.x; i < 65536; i += 256)
    if ((u[i] & 0x7F80u) == 0x7F80u) c = 1;
  if (c) atomicOr(&s, 1);
  __syncthreads();
  if (threadIdx.x == 0) *flag = s;   // 1 = fp32 world, 0 = bf16 world
}

// -------------------- x -> bf16 convert (or copy-through) --------------------
__global__ __launch_bounds__(256) void cvt_k(const void* __restrict__ in,
                                             bf16* __restrict__ out,
                                             const int* __restrict__ flag) {
  const int fl = *flag;
  const size_t i = ((size_t)blockIdx.x * 256 + threadIdx.x) * 8;
  if (fl) {
    f32x4 a = *(const f32x4*)((const float*)in + i);
    f32x4 b = *(const f32x4*)((const float*)in + i + 4);
    bf16x8 o;
#pragma unroll
    for (int j = 0; j < 4; j++) { o[j] = (bf16)a[j]; o[4 + j] = (bf16)b[j]; }
    *(bf16x8*)(out + i) = o;
  } else {
    *(bf16x8*)(out + i) = *(const bf16x8*)((const bf16*)in + i);
  }
}

// ------------- transpose + convert-to-bf16: out[c*R+r] = (bf16)in[r*C+c] -----
__global__ __launch_bounds__(256) void transpose_k(const void* __restrict__ in,
                                                   bf16* __restrict__ out,
                                                   int R, int C,
                                                   const int* __restrict__ flag) {
  __shared__ bf16 tile[32][33];
  const int fl = *flag;
  const int c0 = blockIdx.x * 32, r0 = blockIdx.y * 32;
  const int tx = threadIdx.x & 31, ty = threadIdx.x >> 5;
#pragma unroll
  for (int i = ty; i < 32; i += 8) {
    const size_t idx = (size_t)(r0 + i) * C + c0 + tx;
    tile[i][tx] = fl ? (bf16)((const float*)in)[idx] : ((const bf16*)in)[idx];
  }
  __syncthreads();
#pragma unroll
  for (int i = ty; i < 32; i += 8)
    out[(size_t)(c0 + i) * R + r0 + tx] = tile[tx][i];
}

// ----- GEMM (B pre-transposed): C = A[M,K](lda) @ Bt[N,K]^T [+bias] ----------
template <int EPI, bool AF>
__global__ __launch_bounds__(256) void gemm_bt(const void* __restrict__ Av,
                                               const bf16* __restrict__ Bt,
                                               const void* __restrict__ biasv,
                                               void* __restrict__ Cv,
                                               const int* __restrict__ flag,
                                               size_t aoff, size_t coff,
                                               int M, int N, int K,
                                               int lda, int ldc) {
  const int fl = *flag;
  const bool af32 = AF && (fl != 0);
  __shared__ __align__(16) bf16 sA[128 * 32];
  __shared__ __align__(16) bf16 sB[128 * 32];
  const int tid = threadIdx.x;
  const int lane = tid & 63, wave = tid >> 6;
  const int quad = lane >> 4, l15 = lane & 15;
  const int wr = wave >> 1, wc = wave & 1;
  const int m0 = blockIdx.x * 128, n0 = blockIdx.y * 128;
  const int srow = tid >> 2;          // 0..63
  const int scol = (tid & 3) * 8;     // 0,8,16,24

  f32x4 acc[4][4];
#pragma unroll
  for (int i = 0; i < 4; i++)
#pragma unroll
    for (int j = 0; j < 4; j++) {
      f32x4 z = {0.f, 0.f, 0.f, 0.f};
      acc[i][j] = z;
    }

  const size_t abase0 = aoff + (size_t)(m0 + srow) * lda + scol;
  const size_t abase1 = abase0 + (size_t)64 * lda;
  const bf16* Bg0 = Bt + (size_t)(n0 + srow) * K + scol;
  const bf16* Bg1 = Bg0 + (size_t)64 * K;

  for (int k0 = 0; k0 < K; k0 += 32) {
    bf16x8 a0, a1;
    if (af32) {
      const float* Af = (const float*)Av;
      f32x4 p00 = *(const f32x4*)(Af + abase0 + k0);
      f32x4 p01 = *(const f32x4*)(Af + abase0 + k0 + 4);
      f32x4 p10 = *(const f32x4*)(Af + abase1 + k0);
      f32x4 p11 = *(const f32x4*)(Af + abase1 + k0 + 4);
#pragma unroll
      for (int i = 0; i < 4; i++) {
        a0[i] = (bf16)p00[i]; a0[i + 4] = (bf16)p01[i];
        a1[i] = (bf16)p10[i]; a1[i + 4] = (bf16)p11[i];
      }
    } else {
      const bf16* Ab = (const bf16*)Av;
      a0 = *(const bf16x8*)(Ab + abase0 + k0);
      a1 = *(const bf16x8*)(Ab + abase1 + k0);
    }
    bf16x8 b0 = *(const bf16x8*)(Bg0 + k0);
    bf16x8 b1 = *(const bf16x8*)(Bg1 + k0);
    __syncthreads();
    *(bf16x8*)(sA + srow * 32 + scol) = a0;
    *(bf16x8*)(sA + (64 + srow) * 32 + scol) = a1;
    *(bf16x8*)(sB + srow * 32 + scol) = b0;
    *(bf16x8*)(sB + (64 + srow) * 32 + scol) = b1;
    __syncthreads();

    bf16x8 af[4], bfr[4];
#pragma unroll
    for (int mi = 0; mi < 4; mi++)
      af[mi] = *(const bf16x8*)(sA + (wr * 64 + mi * 16 + l15) * 32 + quad * 8);
#pragma unroll
    for (int ni = 0; ni < 4; ni++)
      bfr[ni] = *(const bf16x8*)(sB + (wc * 64 + ni * 16 + l15) * 32 + quad * 8);
#pragma unroll
    for (int mi = 0; mi < 4; mi++)
#pragma unroll
      for (int ni = 0; ni < 4; ni++)
        acc[mi][ni] = MFMA16(af[mi], bfr[ni], acc[mi][ni]);
  }

#pragma unroll
  for (int mi = 0; mi < 4; mi++) {
#pragma unroll
    for (int r = 0; r < 4; r++) {
      const int m = m0 + wr * 64 + mi * 16 + quad * 4 + r;
#pragma unroll
      for (int ni = 0; ni < 4; ni++) {
        const int n = n0 + wc * 64 + ni * 16 + l15;
        float v = acc[mi][ni][r];
        const size_t idx = coff + (size_t)m * ldc + n;
        if (EPI == 1) {
          v += fl ? ((const float*)biasv)[n] : (float)((const bf16*)biasv)[n];
          if (fl) ((float*)Cv)[idx] = v;
          else    ((bf16*)Cv)[idx] = (bf16)v;
        } else {
          ((bf16*)Cv)[idx] = (bf16)v;
        }
      }
    }
  }
}

// ----- tier-C GEMM (W row-major, in-kernel transpose staging) ----------------
template <int EPI, bool AF, bool WF>
__global__ __launch_bounds__(256) void gemm_nt(const void* __restrict__ Av,
                                               const void* __restrict__ Wv,
                                               const void* __restrict__ biasv,
                                               void* __restrict__ Cv,
                                               const int* __restrict__ flag,
                                               size_t aoff, size_t coff,
                                               int M, int N, int K,
                                               int lda, int ldc) {
  const int fl = *flag;
  const bool af32 = AF && (fl != 0);
  const bool wf32 = WF && (fl != 0);
  __shared__ __align__(16) bf16 sA[128 * 32];
  __shared__ __align__(16) bf16 sB[128 * BSTRIDE];
  const int tid = threadIdx.x;
  const int lane = tid & 63, wave = tid >> 6;
  const int quad = lane >> 4, l15 = lane & 15;
  const int wr = wave >> 1, wc = wave & 1;
  const int m0 = blockIdx.x * 128, n0 = blockIdx.y * 128;
  const int arow = tid >> 2, acol = (tid & 3) * 8;
  const int wk = tid >> 3, wn = (tid & 7) * 16;

  f32x4 acc[4][4];
#pragma unroll
  for (int i = 0; i < 4; i++)
#pragma unroll
    for (int j = 0; j < 4; j++) {
      f32x4 z = {0.f, 0.f, 0.f, 0.f};
      acc[i][j] = z;
    }

  const size_t abase0 = aoff + (size_t)(m0 + arow) * lda + acol;
  const size_t abase1 = abase0 + (size_t)64 * lda;

  for (int k0 = 0; k0 < K; k0 += 32) {
    bf16x8 a0, a1;
    if (af32) {
      const float* Af = (const float*)Av;
      f32x4 p00 = *(const f32x4*)(Af + abase0 + k0);
      f32x4 p01 = *(const f32x4*)(Af + abase0 + k0 + 4);
      f32x4 p10 = *(const f32x4*)(Af + abase1 + k0);
      f32x4 p11 = *(const f32x4*)(Af + abase1 + k0 + 4);
#pragma unroll
      for (int i = 0; i < 4; i++) {
        a0[i] = (bf16)p00[i]; a0[i + 4] = (bf16)p01[i];
        a1[i] = (bf16)p10[i]; a1[i + 4] = (bf16)p11[i];
      }
    } else {
      const bf16* Ab = (const bf16*)Av;
      a0 = *(const bf16x8*)(Ab + abase0 + k0);
      a1 = *(const bf16x8*)(Ab + abase1 + k0);
    }
    bf16 wreg[16];
    const size_t wbase = (size_t)(k0 + wk) * N + n0 + wn;
    if (wf32) {
      const float* Wf = (const float*)Wv;
      f32x4 q0 = *(const f32x4*)(Wf + wbase);
      f32x4 q1 = *(const f32x4*)(Wf + wbase + 4);
      f32x4 q2 = *(const f32x4*)(Wf + wbase + 8);
      f32x4 q3 = *(const f32x4*)(Wf + wbase + 12);
#pragma unroll
      for (int i = 0; i < 4; i++) {
        wreg[i] = (bf16)q0[i];      wreg[4 + i] = (bf16)q1[i];
        wreg[8 + i] = (bf16)q2[i];  wreg[12 + i] = (bf16)q3[i];
      }
    } else {
      const bf16* Wb = (const bf16*)Wv;
      bf16x8 w0 = *(const bf16x8*)(Wb + wbase);
      bf16x8 w1 = *(const bf16x8*)(Wb + wbase + 8);
#pragma unroll
      for (int i = 0; i < 8; i++) { wreg[i] = w0[i]; wreg[8 + i] = w1[i]; }
    }
    __syncthreads();
    *(bf16x8*)(sA + arow * 32 + acol) = a0;
    *(bf16x8*)(sA + (64 + arow) * 32 + acol) = a1;
#pragma unroll
    for (int i = 0; i < 16; i++)
      sB[(wn + i) * BSTRIDE + wk] = wreg[i];
    __syncthreads();

    bf16x8 af[4], bfr[4];
#pragma unroll
    for (int mi = 0; mi < 4; mi++)
      af[mi] = *(const bf16x8*)(sA + (wr * 64 + mi * 16 + l15) * 32 + quad * 8);
#pragma unroll
    for (int ni = 0; ni < 4; ni++)
      bfr[ni] = load_lds8(sB + (wc * 64 + ni * 16 + l15) * BSTRIDE + quad * 8);
#pragma unroll
    for (int mi = 0; mi < 4; mi++)
#pragma unroll
      for (int ni = 0; ni < 4; ni++)
        acc[mi][ni] = MFMA16(af[mi], bfr[ni], acc[mi][ni]);
  }

#pragma unroll
  for (int mi = 0; mi < 4; mi++) {
#pragma unroll
    for (int r = 0; r < 4; r++) {
      const int m = m0 + wr * 64 + mi * 16 + quad * 4 + r;
#pragma unroll
      for (int ni = 0; ni < 4; ni++) {
        const int n = n0 + wc * 64 + ni * 16 + l15;
        float v = acc[mi][ni][r];
        const size_t idx = coff + (size_t)m * ldc + n;
        if (EPI == 1) {
          v += fl ? ((const float*)biasv)[n] : (float)((const bf16*)biasv)[n];
          if (fl) ((float*)Cv)[idx] = v;
          else    ((bf16*)Cv)[idx] = (bf16)v;
        } else {
          ((bf16*)Cv)[idx] = (bf16)v;
        }
      }
    }
  }
}

// -------------------- flash attention, max-free softmax, paired q-tiles ------
// grid: (8, nb*H), block 256. Block x handles q-tiles x and 15-x (128 rows
// each) -> exactly 34 j-tile-units per block, perfectly balanced.
// Softmax is computed WITHOUT a running max: scores are O(+-6) so
// p = exp(s/8) cannot overflow, and softmax is shift-invariant. Row sums l
// are accumulated by MFMA against a constant ones-B-fragment (col 0), so the
// hot loop has ZERO cross-lane shuffles. O and l are normalized at the end.
__global__ __launch_bounds__(256) void attn_k(bf16* __restrict__ qkv) {
  __shared__ __align__(16) bf16 sQ[128 * LDSS];   // wave regions reused for P
  __shared__ __align__(16) bf16 sK[64 * LDSS];
  __shared__ __align__(16) bf16 sVt[64 * LDSS];   // [dim][key]

  const int tid = threadIdx.x;
  const int lane = tid & 63, wave = tid >> 6;
  const int quad = lane >> 4, l15 = lane & 15;
  const int bh = blockIdx.y;
  bf16* base = qkv + (size_t)(bh >> 4) * TT * N_QKV + (bh & 15) * DD;
  const bf16* Qp = base;
  const bf16* Kp = base + CC;
  const bf16* Vp = base + 2 * CC;

  const int krow = tid >> 2;          // 0..63
  const int kcol = (tid & 3) * 16;    // 0,16,32,48
  const int vkey = tid & 31;          // 0..31
  const int vcol = (tid >> 5) * 8;    // 0..56

  // ones B-fragment: column 0 of the virtual "l-tile" is all-ones
  bf16x8 ones;
  {
    const bf16 o = (l15 == 0) ? (bf16)1.0f : (bf16)0.0f;
#pragma unroll
    for (int i = 0; i < 8; i++) ones[i] = o;
  }

  for (int pass = 0; pass < 2; pass++) {
    const int qt = pass ? (15 - (int)blockIdx.x) : (int)blockIdx.x;
    const int q0 = qt * 128;
    __syncthreads();   // prior pass's LDS fully consumed

    // ---- stage Q (pre-scaled by 1/sqrt(D)) ----
#pragma unroll
    for (int p = 0; p < 2; p++) {
      const int r = p * 64 + krow;
      const bf16* src = Qp + (size_t)(q0 + r) * N_QKV + kcol;
      bf16x8 v0 = *(const bf16x8*)src;
      bf16x8 v1 = *(const bf16x8*)(src + 8);
#pragma unroll
      for (int i = 0; i < 8; i++) {
        v0[i] = (bf16)((float)v0[i] * QSCALE);
        v1[i] = (bf16)((float)v1[i] * QSCALE);
      }
      store_lds8(sQ + r * LDSS + kcol, v0);
      store_lds8(sQ + r * LDSS + kcol + 8, v1);
    }

    // prefetch K/V tile 0 (overlaps barrier + aq loads)
    bf16x8 kr0, kr1, vr0, vr1;
    {
      const bf16* kp = Kp + (size_t)krow * N_QKV + kcol;
      kr0 = *(const bf16x8*)kp;
      kr1 = *(const bf16x8*)(kp + 8);
      vr0 = *(const bf16x8*)(Vp + (size_t)vkey * N_QKV + vcol);
      vr1 = *(const bf16x8*)(Vp + (size_t)(32 + vkey) * N_QKV + vcol);
    }
    __syncthreads();

    bf16x8 aq[2][2];
#pragma unroll
    for (int mi = 0; mi < 2; mi++) {
      const bf16* qp = sQ + (size_t)(wave * 32 + mi * 16 + l15) * LDSS + quad * 8;
      aq[mi][0] = load_lds8(qp);
      aq[mi][1] = load_lds8(qp + 32);
    }

    f32x4 Oacc[2][4];
    f32x4 lacc[2];
#pragma unroll
    for (int mi = 0; mi < 2; mi++) {
      f32x4 z = {0.f, 0.f, 0.f, 0.f};
      lacc[mi] = z;
#pragma unroll
      for (int nt = 0; nt < 4; nt++) Oacc[mi][nt] = z;
    }

    const int jmax = q0 + 64;
    const int wave_row0 = q0 + wave * 32;
    bf16* sP = sQ + (size_t)(wave * 32) * LDSS;   // wave-private P region

    for (int j0 = 0; j0 <= jmax; j0 += 64) {
      __syncthreads();
      store_lds8(sK + krow * LDSS + kcol, kr0);
      store_lds8(sK + krow * LDSS + kcol + 8, kr1);
#pragma unroll
      for (int i = 0; i < 8; i++) {
        sVt[(vcol + i) * LDSS + vkey] = vr0[i];
        sVt[(vcol + i) * LDSS + 32 + vkey] = vr1[i];
      }
      __syncthreads();

      if (j0 + 64 <= jmax) {          // prefetch next tile (overlaps compute)
        const bf16* kp = Kp + (size_t)(j0 + 64 + krow) * N_QKV + kcol;
        kr0 = *(const bf16x8*)kp;
        kr1 = *(const bf16x8*)(kp + 8);
        vr0 = *(const bf16x8*)(Vp + (size_t)(j0 + 64 + vkey) * N_QKV + vcol);
        vr1 = *(const bf16x8*)(Vp + (size_t)(j0 + 96 + vkey) * N_QKV + vcol);
      }

      if (j0 <= wave_row0 + 31) {     // skip fully-masked tiles (wave-uniform)
        // ---- S = (Q/8) K^T ----
        f32x4 S[2][4];
#pragma unroll
        for (int nt = 0; nt < 4; nt++) {
          const bf16* kp = sK + (size_t)(nt * 16 + l15) * LDSS + quad * 8;
          bf16x8 bk0 = load_lds8(kp);
          bf16x8 bk1 = load_lds8(kp + 32);
#pragma unroll
          for (int mi = 0; mi < 2; mi++) {
            f32x4 acc = {0.f, 0.f, 0.f, 0.f};
            acc = MFMA16(aq[mi][0], bk0, acc);
            acc = MFMA16(aq[mi][1], bk1, acc);
            S[mi][nt] = acc;
          }
        }

        // ---- p = exp(s), causal mask on boundary tiles only ----
        const bool needmask = (j0 + 63 > wave_row0);
#pragma unroll
        for (int mi = 0; mi < 2; mi++)
#pragma unroll
          for (int nt = 0; nt < 4; nt++) {
            const int kc = j0 + nt * 16 + l15;
#pragma unroll
            for (int r = 0; r < 4; r++) {
              const float e = __expf(S[mi][nt][r]);
              const bool dead =
                  needmask && (kc > wave_row0 + mi * 16 + quad * 4 + r);
              const float pv = dead ? 0.f : e;
              sP[(size_t)(mi * 16 + quad * 4 + r) * LDSS + nt * 16 + l15] =
                  (bf16)pv;
            }
          }

        // ---- O += P V ; l += P 1 (via ones-fragment MFMA) ----
        bf16x8 ap[2][2];
#pragma unroll
        for (int mi = 0; mi < 2; mi++) {
          const bf16* pp = sP + (size_t)(mi * 16 + l15) * LDSS + quad * 8;
          ap[mi][0] = load_lds8(pp);
          ap[mi][1] = load_lds8(pp + 32);
          lacc[mi] = MFMA16(ap[mi][0], ones, lacc[mi]);
          lacc[mi] = MFMA16(ap[mi][1], ones, lacc[mi]);
        }
#pragma unroll
        for (int nt = 0; nt < 4; nt++) {
          const bf16* vp = sVt + (size_t)(nt * 16 + l15) * LDSS + quad * 8;
          bf16x8 bv0 = load_lds8(vp);
          bf16x8 bv1 = load_lds8(vp + 32);
#pragma unroll
          for (int mi = 0; mi < 2; mi++) {
            Oacc[mi][nt] = MFMA16(ap[mi][0], bv0, Oacc[mi][nt]);
            Oacc[mi][nt] = MFMA16(ap[mi][1], bv1, Oacc[mi][nt]);
          }
        }
      }
    }

    // ---- epilogue: l lives on l15==0 lanes; broadcast and normalize ----
#pragma unroll
    for (int mi = 0; mi < 2; mi++)
#pragma unroll
      for (int r = 0; r < 4; r++) {
        const float lv = __shfl(lacc[mi][r], lane & 48, 64);
        const float invl = 1.0f / lv;
        const int t = q0 + wave * 32 + mi * 16 + quad * 4 + r;
#pragma unroll
        for (int nt = 0; nt < 4; nt++)
          base[(size_t)t * N_QKV + nt * 16 + l15] =
              (bf16)(Oacc[mi][nt][r] * invl);
      }
  }
}

// -------------------- launch --------------------
extern "C" void kernel_launch(void* const* d_in, const int* in_sizes, int n_in,
                              void* d_out, int out_size, void* d_ws, size_t ws_size,
                              hipStream_t stream) {
  const void* x = d_in[0];       // [8192,1024] fp32 or bf16
  const void* w_qkv = d_in[1];   // [1024,3072]
  const void* w_out = d_in[2];   // [1024,1024]
  const void* b_out = d_in[3];   // [1024]

  int* flag = (int*)d_ws;
  char* p = (char*)d_ws + 256;
  bf16* wqkvT = (bf16*)p;                          // [3072,1024]  6 MB
  bf16* woutT = wqkvT + (size_t)N_QKV * CC;        // [1024,1024]  2 MB

  const size_t wT_bytes = ((size_t)N_QKV * CC + (size_t)CC * CC) * 2;  // 8 MB
  const size_t xb_bytes = (size_t)MM * CC * 2;                         // 16 MB
  const size_t qkv_bytes = (size_t)MM * N_QKV * 2;                     // 48 MB
  const size_t need_Ap = 256 + wT_bytes + xb_bytes + qkv_bytes;
  const size_t need_A  = 256 + wT_bytes + qkv_bytes;
  const size_t need_B  = 256 + wT_bytes + (size_t)TT * N_QKV * 2;

  sniff_k<<<1, 256, 0, stream>>>((const unsigned short*)x, flag);

  if (ws_size >= need_Ap) {
    // ---- Tier A+: fused, pre-converted bf16 x ----
    bf16* xb = woutT + (size_t)CC * CC;
    bf16* qkv = xb + (size_t)MM * CC;
    cvt_k<<<(MM * CC) / 2048, 256, 0, stream>>>(x, xb, flag);
    transpose_k<<<dim3(N_QKV / 32, CC / 32), 256, 0, stream>>>(w_qkv, wqkvT, CC, N_QKV, flag);
    transpose_k<<<dim3(CC / 32, CC / 32), 256, 0, stream>>>(w_out, woutT, CC, CC, flag);

    gemm_bt<0, false><<<dim3(MM / 128, N_QKV / 128), 256, 0, stream>>>(
        xb, wqkvT, nullptr, qkv, flag, 0, 0, MM, N_QKV, CC, CC, N_QKV);

    attn_k<<<dim3(8, BB * HH), 256, 0, stream>>>(qkv);

    gemm_bt<1, false><<<dim3(MM / 128, CC / 128), 256, 0, stream>>>(
        qkv, woutT, b_out, d_out, flag, 0, 0, MM, CC, CC, N_QKV, CC);
  } else if (ws_size >= need_A) {
    // ---- Tier A: fused ----
    bf16* qkv = woutT + (size_t)CC * CC;
    transpose_k<<<dim3(N_QKV / 32, CC / 32), 256, 0, stream>>>(w_qkv, wqkvT, CC, N_QKV, flag);
    transpose_k<<<dim3(CC / 32, CC / 32), 256, 0, stream>>>(w_out, woutT, CC, CC, flag);

    gemm_bt<0, true><<<dim3(MM / 128, N_QKV / 128), 256, 0, stream>>>(
        x, wqkvT, nullptr, qkv, flag, 0, 0, MM, N_QKV, CC, CC, N_QKV);

    attn_k<<<dim3(8, BB * HH), 256, 0, stream>>>(qkv);

    gemm_bt<1, false><<<dim3(MM / 128, CC / 128), 256, 0, stream>>>(
        qkv, woutT, b_out, d_out, flag, 0, 0, MM, CC, CC, N_QKV, CC);
  } else if (ws_size >= need_B) {
    // ---- Tier B: per-batch, pre-transposed weights ----
    bf16* qkv = woutT + (size_t)CC * CC;
    transpose_k<<<dim3(N_QKV / 32, CC / 32), 256, 0, stream>>>(w_qkv, wqkvT, CC, N_QKV, flag);
    transpose_k<<<dim3(CC / 32, CC / 32), 256, 0, stream>>>(w_out, woutT, CC, CC, flag);
    for (int b = 0; b < BB; b++) {
      const size_t xoff = (size_t)b * TT * CC;
      gemm_bt<0, true><<<dim3(TT / 128, N_QKV / 128), 256, 0, stream>>>(
          x, wqkvT, nullptr, qkv, flag, xoff, 0, TT, N_QKV, CC, CC, N_QKV);
      attn_k<<<dim3(8, HH), 256, 0, stream>>>(qkv);
      gemm_bt<1, false><<<dim3(TT / 128, CC / 128), 256, 0, stream>>>(
          qkv, woutT, b_out, d_out, flag, 0, xoff, TT, CC, CC, N_QKV, CC);
    }
  } else {
    // ---- Tier C: minimal ws ----
    bf16* qkvb = (bf16*)p;
    for (int b = 0; b < BB; b++) {
      const size_t xoff = (size_t)b * TT * CC;
      gemm_nt<0, true, true><<<dim3(TT / 128, N_QKV / 128), 256, 0, stream>>>(
          x, w_qkv, nullptr, qkvb, flag, xoff, 0, TT, N_QKV, CC, CC, N_QKV);
      attn_k<<<dim3(8, HH), 256, 0, stream>>>(qkvb);
      gemm_nt<1, false, true><<<dim3(TT / 128, CC / 128), 256, 0, stream>>>(
          qkvb, w_out, b_out, d_out, flag, 0, xoff, TT, CC, CC, N_QKV, CC);
    }
  }
}

// Round 8
// 332.585 us; speedup vs baseline: 3.0207x; 1.0064x over previous
//
#include <hip/hip_runtime.h>

typedef __bf16 bf16;
typedef __bf16 bf16x4 __attribute__((ext_vector_type(4)));
typedef __bf16 bf16x8 __attribute__((ext_vector_type(8)));
typedef float  f32x4  __attribute__((ext_vector_type(4)));

#define MFMA16(A_, B_, C_) __builtin_amdgcn_mfma_f32_16x16x32_bf16((A_), (B_), (C_), 0, 0, 0)

// ---- constants ----
#define BB 4
#define TT 2048
#define CC 1024
#define HH 16
#define DD 64
#define MM (BB * TT)         // 8192
#define N_QKV (3 * CC)       // 3072
#define LDSS 68              // padded LDS row stride for attention tiles
#define BSTRIDE 36           // tier-C sB row stride
// 1/sqrt(D) * log2(e): p = exp(s/8) computed as exp2(s * QSCALE2) -> 1 v_exp
#define QSCALE2 0.18033688f

static __device__ __forceinline__ void store_lds8(bf16* p, bf16x8 v) {
  bf16x4 lo, hi;
#pragma unroll
  for (int i = 0; i < 4; i++) { lo[i] = v[i]; hi[i] = v[i + 4]; }
  *(bf16x4*)p = lo;
  *(bf16x4*)(p + 4) = hi;
}

static __device__ __forceinline__ bf16x8 load_lds8(const bf16* p) {
  bf16x4 lo = *(const bf16x4*)p;
  bf16x4 hi = *(const bf16x4*)(p + 4);
  bf16x8 v;
#pragma unroll
  for (int i = 0; i < 4; i++) { v[i] = lo[i]; v[i + 4] = hi[i]; }
  return v;
}

// async global->LDS, 16 B per lane; LDS dest = wave-uniform base + lane*16
static __device__ __forceinline__ void async_cp16(const bf16* g, bf16* l) {
  __builtin_amdgcn_global_load_lds(
      (const __attribute__((address_space(1))) void*)g,
      (__attribute__((address_space(3))) void*)l, 16, 0, 0);
}

// -------------------- dtype sniff --------------------
__global__ __launch_bounds__(256) void sniff_k(const unsigned short* __restrict__ u,
                                               int* __restrict__ flag) {
  __shared__ int s;
  if (threadIdx.x == 0) s = 0;
  __syncthreads();
  int c = 0;
  for (int i = threadIdx.x; i < 65536; i += 256)
    if ((u[i] & 0x7F80u) == 0x7F80u) c = 1;
  if (c) atomicOr(&s, 1);
  __syncthreads();
  if (threadIdx.x == 0) *flag = s;   // 1 = fp32 world, 0 = bf16 world
}

// -------------------- x -> bf16 convert (or copy-through) --------------------
__global__ __launch_bounds__(256) void cvt_k(const void* __restrict__ in,
                                             bf16* __restrict__ out,
                                             const int* __restrict__ flag) {
  const int fl = *flag;
  const size_t i = ((size_t)blockIdx.x * 256 + threadIdx.x) * 8;
  if (fl) {
    f32x4 a = *(const f32x4*)((const float*)in + i);
    f32x4 b = *(const f32x4*)((const float*)in + i + 4);
    bf16x8 o;
#pragma unroll
    for (int j = 0; j < 4; j++) { o[j] = (bf16)a[j]; o[4 + j] = (bf16)b[j]; }
    *(bf16x8*)(out + i) = o;
  } else {
    *(bf16x8*)(out + i) = *(const bf16x8*)((const bf16*)in + i);
  }
}

// ------------- transpose + convert-to-bf16: out[c*R+r] = (bf16)in[r*C+c] -----
__global__ __launch_bounds__(256) void transpose_k(const void* __restrict__ in,
                                                   bf16* __restrict__ out,
                                                   int R, int C,
                                                   const int* __restrict__ flag) {
  __shared__ bf16 tile[32][33];
  const int fl = *flag;
  const int c0 = blockIdx.x * 32, r0 = blockIdx.y * 32;
  const int tx = threadIdx.x & 31, ty = threadIdx.x >> 5;
#pragma unroll
  for (int i = ty; i < 32; i += 8) {
    const size_t idx = (size_t)(r0 + i) * C + c0 + tx;
    tile[i][tx] = fl ? (bf16)((const float*)in)[idx] : ((const bf16*)in)[idx];
  }
  __syncthreads();
#pragma unroll
  for (int i = ty; i < 32; i += 8)
    out[(size_t)(c0 + i) * R + r0 + tx] = tile[tx][i];
}

// ----- GEMM, all-bf16, global_load_lds staging (m97 ladder step 3) -----------
// C = A[M,K](lda) @ Bt[N,K]^T [+bias]; EPI=1 adds bias, out dtype per flag.
template <int EPI>
__global__ __launch_bounds__(256) void gemm_lds(const bf16* __restrict__ A,
                                                const bf16* __restrict__ Bt,
                                                const void* __restrict__ biasv,
                                                void* __restrict__ Cv,
                                                const int* __restrict__ flag,
                                                size_t aoff, size_t coff,
                                                int M, int N, int K,
                                                int lda, int ldc) {
  const int fl = *flag;
  __shared__ __align__(16) bf16 sA[128 * 32];   // unpadded: lds-direct layout
  __shared__ __align__(16) bf16 sB[128 * 32];
  const int tid = threadIdx.x;
  const int lane = tid & 63, wave = tid >> 6;
  const int quad = lane >> 4, l15 = lane & 15;
  const int wr = wave >> 1, wc = wave & 1;
  const int m0 = blockIdx.x * 128, n0 = blockIdx.y * 128;
  const int grow = lane >> 2;         // 0..15
  const int gcol = (lane & 3) * 8;    // 0,8,16,24

  f32x4 acc[4][4];
#pragma unroll
  for (int i = 0; i < 4; i++)
#pragma unroll
    for (int j = 0; j < 4; j++) {
      f32x4 z = {0.f, 0.f, 0.f, 0.f};
      acc[i][j] = z;
    }

  // wave w stages rows [w*32, w*32+32) of each 128x32 tile, 2 calls of 16 rows
  const bf16* Ag = A + aoff + (size_t)(m0 + wave * 32 + grow) * lda + gcol;
  const bf16* Bg = Bt + (size_t)(n0 + wave * 32 + grow) * K + gcol;
  bf16* sAw = sA + wave * 32 * 32;
  bf16* sBw = sB + wave * 32 * 32;

  for (int k0 = 0; k0 < K; k0 += 32) {
    __syncthreads();                  // prior iter's frag reads done
    async_cp16(Ag, sAw);
    async_cp16(Ag + (size_t)16 * lda, sAw + 16 * 32);
    async_cp16(Bg, sBw);
    async_cp16(Bg + (size_t)16 * K, sBw + 16 * 32);
    Ag += 32;
    Bg += 32;
    __syncthreads();                  // vmcnt(0) drain inserted by compiler

    bf16x8 af[4], bfr[4];
#pragma unroll
    for (int mi = 0; mi < 4; mi++)
      af[mi] = *(const bf16x8*)(sA + (wr * 64 + mi * 16 + l15) * 32 + quad * 8);
#pragma unroll
    for (int ni = 0; ni < 4; ni++)
      bfr[ni] = *(const bf16x8*)(sB + (wc * 64 + ni * 16 + l15) * 32 + quad * 8);
#pragma unroll
    for (int mi = 0; mi < 4; mi++)
#pragma unroll
      for (int ni = 0; ni < 4; ni++)
        acc[mi][ni] = MFMA16(af[mi], bfr[ni], acc[mi][ni]);
  }

#pragma unroll
  for (int mi = 0; mi < 4; mi++) {
#pragma unroll
    for (int r = 0; r < 4; r++) {
      const int m = m0 + wr * 64 + mi * 16 + quad * 4 + r;
#pragma unroll
      for (int ni = 0; ni < 4; ni++) {
        const int n = n0 + wc * 64 + ni * 16 + l15;
        float v = acc[mi][ni][r];
        const size_t idx = coff + (size_t)m * ldc + n;
        if (EPI == 1) {
          v += fl ? ((const float*)biasv)[n] : (float)((const bf16*)biasv)[n];
          if (fl) ((float*)Cv)[idx] = v;
          else    ((bf16*)Cv)[idx] = (bf16)v;
        } else {
          ((bf16*)Cv)[idx] = (bf16)v;
        }
      }
    }
  }
}

// ----- GEMM (B pre-transposed, register staging; A may be fp32) --------------
template <int EPI, bool AF>
__global__ __launch_bounds__(256) void gemm_bt(const void* __restrict__ Av,
                                               const bf16* __restrict__ Bt,
                                               const void* __restrict__ biasv,
                                               void* __restrict__ Cv,
                                               const int* __restrict__ flag,
                                               size_t aoff, size_t coff,
                                               int M, int N, int K,
                                               int lda, int ldc) {
  const int fl = *flag;
  const bool af32 = AF && (fl != 0);
  __shared__ __align__(16) bf16 sA[128 * 32];
  __shared__ __align__(16) bf16 sB[128 * 32];
  const int tid = threadIdx.x;
  const int lane = tid & 63, wave = tid >> 6;
  const int quad = lane >> 4, l15 = lane & 15;
  const int wr = wave >> 1, wc = wave & 1;
  const int m0 = blockIdx.x * 128, n0 = blockIdx.y * 128;
  const int srow = tid >> 2;          // 0..63
  const int scol = (tid & 3) * 8;     // 0,8,16,24

  f32x4 acc[4][4];
#pragma unroll
  for (int i = 0; i < 4; i++)
#pragma unroll
    for (int j = 0; j < 4; j++) {
      f32x4 z = {0.f, 0.f, 0.f, 0.f};
      acc[i][j] = z;
    }

  const size_t abase0 = aoff + (size_t)(m0 + srow) * lda + scol;
  const size_t abase1 = abase0 + (size_t)64 * lda;
  const bf16* Bg0 = Bt + (size_t)(n0 + srow) * K + scol;
  const bf16* Bg1 = Bg0 + (size_t)64 * K;

  for (int k0 = 0; k0 < K; k0 += 32) {
    bf16x8 a0, a1;
    if (af32) {
      const float* Af = (const float*)Av;
      f32x4 p00 = *(const f32x4*)(Af + abase0 + k0);
      f32x4 p01 = *(const f32x4*)(Af + abase0 + k0 + 4);
      f32x4 p10 = *(const f32x4*)(Af + abase1 + k0);
      f32x4 p11 = *(const f32x4*)(Af + abase1 + k0 + 4);
#pragma unroll
      for (int i = 0; i < 4; i++) {
        a0[i] = (bf16)p00[i]; a0[i + 4] = (bf16)p01[i];
        a1[i] = (bf16)p10[i]; a1[i + 4] = (bf16)p11[i];
      }
    } else {
      const bf16* Ab = (const bf16*)Av;
      a0 = *(const bf16x8*)(Ab + abase0 + k0);
      a1 = *(const bf16x8*)(Ab + abase1 + k0);
    }
    bf16x8 b0 = *(const bf16x8*)(Bg0 + k0);
    bf16x8 b1 = *(const bf16x8*)(Bg1 + k0);
    __syncthreads();
    *(bf16x8*)(sA + srow * 32 + scol) = a0;
    *(bf16x8*)(sA + (64 + srow) * 32 + scol) = a1;
    *(bf16x8*)(sB + srow * 32 + scol) = b0;
    *(bf16x8*)(sB + (64 + srow) * 32 + scol) = b1;
    __syncthreads();

    bf16x8 af[4], bfr[4];
#pragma unroll
    for (int mi = 0; mi < 4; mi++)
      af[mi] = *(const bf16x8*)(sA + (wr * 64 + mi * 16 + l15) * 32 + quad * 8);
#pragma unroll
    for (int ni = 0; ni < 4; ni++)
      bfr[ni] = *(const bf16x8*)(sB + (wc * 64 + ni * 16 + l15) * 32 + quad * 8);
#pragma unroll
    for (int mi = 0; mi < 4; mi++)
#pragma unroll
      for (int ni = 0; ni < 4; ni++)
        acc[mi][ni] = MFMA16(af[mi], bfr[ni], acc[mi][ni]);
  }

#pragma unroll
  for (int mi = 0; mi < 4; mi++) {
#pragma unroll
    for (int r = 0; r < 4; r++) {
      const int m = m0 + wr * 64 + mi * 16 + quad * 4 + r;
#pragma unroll
      for (int ni = 0; ni < 4; ni++) {
        const int n = n0 + wc * 64 + ni * 16 + l15;
        float v = acc[mi][ni][r];
        const size_t idx = coff + (size_t)m * ldc + n;
        if (EPI == 1) {
          v += fl ? ((const float*)biasv)[n] : (float)((const bf16*)biasv)[n];
          if (fl) ((float*)Cv)[idx] = v;
          else    ((bf16*)Cv)[idx] = (bf16)v;
        } else {
          ((bf16*)Cv)[idx] = (bf16)v;
        }
      }
    }
  }
}

// ----- tier-C GEMM (W row-major, in-kernel transpose staging) ----------------
template <int EPI, bool AF, bool WF>
__global__ __launch_bounds__(256) void gemm_nt(const void* __restrict__ Av,
                                               const void* __restrict__ Wv,
                                               const void* __restrict__ biasv,
                                               void* __restrict__ Cv,
                                               const int* __restrict__ flag,
                                               size_t aoff, size_t coff,
                                               int M, int N, int K,
                                               int lda, int ldc) {
  const int fl = *flag;
  const bool af32 = AF && (fl != 0);
  const bool wf32 = WF && (fl != 0);
  __shared__ __align__(16) bf16 sA[128 * 32];
  __shared__ __align__(16) bf16 sB[128 * BSTRIDE];
  const int tid = threadIdx.x;
  const int lane = tid & 63, wave = tid >> 6;
  const int quad = lane >> 4, l15 = lane & 15;
  const int wr = wave >> 1, wc = wave & 1;
  const int m0 = blockIdx.x * 128, n0 = blockIdx.y * 128;
  const int arow = tid >> 2, acol = (tid & 3) * 8;
  const int wk = tid >> 3, wn = (tid & 7) * 16;

  f32x4 acc[4][4];
#pragma unroll
  for (int i = 0; i < 4; i++)
#pragma unroll
    for (int j = 0; j < 4; j++) {
      f32x4 z = {0.f, 0.f, 0.f, 0.f};
      acc[i][j] = z;
    }

  const size_t abase0 = aoff + (size_t)(m0 + arow) * lda + acol;
  const size_t abase1 = abase0 + (size_t)64 * lda;

  for (int k0 = 0; k0 < K; k0 += 32) {
    bf16x8 a0, a1;
    if (af32) {
      const float* Af = (const float*)Av;
      f32x4 p00 = *(const f32x4*)(Af + abase0 + k0);
      f32x4 p01 = *(const f32x4*)(Af + abase0 + k0 + 4);
      f32x4 p10 = *(const f32x4*)(Af + abase1 + k0);
      f32x4 p11 = *(const f32x4*)(Af + abase1 + k0 + 4);
#pragma unroll
      for (int i = 0; i < 4; i++) {
        a0[i] = (bf16)p00[i]; a0[i + 4] = (bf16)p01[i];
        a1[i] = (bf16)p10[i]; a1[i + 4] = (bf16)p11[i];
      }
    } else {
      const bf16* Ab = (const bf16*)Av;
      a0 = *(const bf16x8*)(Ab + abase0 + k0);
      a1 = *(const bf16x8*)(Ab + abase1 + k0);
    }
    bf16 wreg[16];
    const size_t wbase = (size_t)(k0 + wk) * N + n0 + wn;
    if (wf32) {
      const float* Wf = (const float*)Wv;
      f32x4 q0 = *(const f32x4*)(Wf + wbase);
      f32x4 q1 = *(const f32x4*)(Wf + wbase + 4);
      f32x4 q2 = *(const f32x4*)(Wf + wbase + 8);
      f32x4 q3 = *(const f32x4*)(Wf + wbase + 12);
#pragma unroll
      for (int i = 0; i < 4; i++) {
        wreg[i] = (bf16)q0[i];      wreg[4 + i] = (bf16)q1[i];
        wreg[8 + i] = (bf16)q2[i];  wreg[12 + i] = (bf16)q3[i];
      }
    } else {
      const bf16* Wb = (const bf16*)Wv;
      bf16x8 w0 = *(const bf16x8*)(Wb + wbase);
      bf16x8 w1 = *(const bf16x8*)(Wb + wbase + 8);
#pragma unroll
      for (int i = 0; i < 8; i++) { wreg[i] = w0[i]; wreg[8 + i] = w1[i]; }
    }
    __syncthreads();
    *(bf16x8*)(sA + arow * 32 + acol) = a0;
    *(bf16x8*)(sA + (64 + arow) * 32 + acol) = a1;
#pragma unroll
    for (int i = 0; i < 16; i++)
      sB[(wn + i) * BSTRIDE + wk] = wreg[i];
    __syncthreads();

    bf16x8 af[4], bfr[4];
#pragma unroll
    for (int mi = 0; mi < 4; mi++)
      af[mi] = *(const bf16x8*)(sA + (wr * 64 + mi * 16 + l15) * 32 + quad * 8);
#pragma unroll
    for (int ni = 0; ni < 4; ni++)
      bfr[ni] = load_lds8(sB + (wc * 64 + ni * 16 + l15) * BSTRIDE + quad * 8);
#pragma unroll
    for (int mi = 0; mi < 4; mi++)
#pragma unroll
      for (int ni = 0; ni < 4; ni++)
        acc[mi][ni] = MFMA16(af[mi], bfr[ni], acc[mi][ni]);
  }

#pragma unroll
  for (int mi = 0; mi < 4; mi++) {
#pragma unroll
    for (int r = 0; r < 4; r++) {
      const int m = m0 + wr * 64 + mi * 16 + quad * 4 + r;
#pragma unroll
      for (int ni = 0; ni < 4; ni++) {
        const int n = n0 + wc * 64 + ni * 16 + l15;
        float v = acc[mi][ni][r];
        const size_t idx = coff + (size_t)m * ldc + n;
        if (EPI == 1) {
          v += fl ? ((const float*)biasv)[n] : (float)((const bf16*)biasv)[n];
          if (fl) ((float*)Cv)[idx] = v;
          else    ((bf16*)Cv)[idx] = (bf16)v;
        } else {
          ((bf16*)Cv)[idx] = (bf16)v;
        }
      }
    }
  }
}

// -------------------- flash attention, max-free softmax, paired q-tiles ------
// grid: (8, nb*H), block 256. Block x handles q-tiles x and 15-x (128 rows
// each) -> exactly 34 j-tile-units per block. p = exp2(s*0.125*log2e) (scale
// folded into staged Q); row sums l via MFMA against a ones-B-fragment.
__global__ __launch_bounds__(256) void attn_k(bf16* __restrict__ qkv) {
  __shared__ __align__(16) bf16 sQ[128 * LDSS];   // wave regions reused for P
  __shared__ __align__(16) bf16 sK[64 * LDSS];
  __shared__ __align__(16) bf16 sVt[64 * LDSS];   // [dim][key]

  const int tid = threadIdx.x;
  const int lane = tid & 63, wave = tid >> 6;
  const int quad = lane >> 4, l15 = lane & 15;
  const int bh = blockIdx.y;
  bf16* base = qkv + (size_t)(bh >> 4) * TT * N_QKV + (bh & 15) * DD;
  const bf16* Qp = base;
  const bf16* Kp = base + CC;
  const bf16* Vp = base + 2 * CC;

  const int krow = tid >> 2;          // 0..63
  const int kcol = (tid & 3) * 16;    // 0,16,32,48
  const int vkey = tid & 31;          // 0..31
  const int vcol = (tid >> 5) * 8;    // 0..56

  bf16x8 ones;
  {
    const bf16 o = (l15 == 0) ? (bf16)1.0f : (bf16)0.0f;
#pragma unroll
    for (int i = 0; i < 8; i++) ones[i] = o;
  }

  for (int pass = 0; pass < 2; pass++) {
    const int qt = pass ? (15 - (int)blockIdx.x) : (int)blockIdx.x;
    const int q0 = qt * 128;
    __syncthreads();   // prior pass's LDS fully consumed

    // ---- stage Q (pre-scaled by QSCALE2) ----
#pragma unroll
    for (int p = 0; p < 2; p++) {
      const int r = p * 64 + krow;
      const bf16* src = Qp + (size_t)(q0 + r) * N_QKV + kcol;
      bf16x8 v0 = *(const bf16x8*)src;
      bf16x8 v1 = *(const bf16x8*)(src + 8);
#pragma unroll
      for (int i = 0; i < 8; i++) {
        v0[i] = (bf16)((float)v0[i] * QSCALE2);
        v1[i] = (bf16)((float)v1[i] * QSCALE2);
      }
      store_lds8(sQ + r * LDSS + kcol, v0);
      store_lds8(sQ + r * LDSS + kcol + 8, v1);
    }

    // prefetch K/V tile 0
    bf16x8 kr0, kr1, vr0, vr1;
    {
      const bf16* kp = Kp + (size_t)krow * N_QKV + kcol;
      kr0 = *(const bf16x8*)kp;
      kr1 = *(const bf16x8*)(kp + 8);
      vr0 = *(const bf16x8*)(Vp + (size_t)vkey * N_QKV + vcol);
      vr1 = *(const bf16x8*)(Vp + (size_t)(32 + vkey) * N_QKV + vcol);
    }
    __syncthreads();

    bf16x8 aq[2][2];
#pragma unroll
    for (int mi = 0; mi < 2; mi++) {
      const bf16* qp = sQ + (size_t)(wave * 32 + mi * 16 + l15) * LDSS + quad * 8;
      aq[mi][0] = load_lds8(qp);
      aq[mi][1] = load_lds8(qp + 32);
    }

    f32x4 Oacc[2][4];
    f32x4 lacc[2];
#pragma unroll
    for (int mi = 0; mi < 2; mi++) {
      f32x4 z = {0.f, 0.f, 0.f, 0.f};
      lacc[mi] = z;
#pragma unroll
      for (int nt = 0; nt < 4; nt++) Oacc[mi][nt] = z;
    }

    const int jmax = q0 + 64;
    const int wave_row0 = q0 + wave * 32;
    bf16* sP = sQ + (size_t)(wave * 32) * LDSS;   // wave-private P region

    for (int j0 = 0; j0 <= jmax; j0 += 64) {
      __syncthreads();
      store_lds8(sK + krow * LDSS + kcol, kr0);
      store_lds8(sK + krow * LDSS + kcol + 8, kr1);
#pragma unroll
      for (int i = 0; i < 8; i++) {
        sVt[(vcol + i) * LDSS + vkey] = vr0[i];
        sVt[(vcol + i) * LDSS + 32 + vkey] = vr1[i];
      }
      __syncthreads();

      if (j0 + 64 <= jmax) {          // prefetch next tile (overlaps compute)
        const bf16* kp = Kp + (size_t)(j0 + 64 + krow) * N_QKV + kcol;
        kr0 = *(const bf16x8*)kp;
        kr1 = *(const bf16x8*)(kp + 8);
        vr0 = *(const bf16x8*)(Vp + (size_t)(j0 + 64 + vkey) * N_QKV + vcol);
        vr1 = *(const bf16x8*)(Vp + (size_t)(j0 + 96 + vkey) * N_QKV + vcol);
      }

      if (j0 <= wave_row0 + 31) {     // skip fully-masked tiles (wave-uniform)
        // ---- S = (Q*QSCALE2) K^T ----
        f32x4 S[2][4];
#pragma unroll
        for (int nt = 0; nt < 4; nt++) {
          const bf16* kp = sK + (size_t)(nt * 16 + l15) * LDSS + quad * 8;
          bf16x8 bk0 = load_lds8(kp);
          bf16x8 bk1 = load_lds8(kp + 32);
#pragma unroll
          for (int mi = 0; mi < 2; mi++) {
            f32x4 acc = {0.f, 0.f, 0.f, 0.f};
            acc = MFMA16(aq[mi][0], bk0, acc);
            acc = MFMA16(aq[mi][1], bk1, acc);
            S[mi][nt] = acc;
          }
        }

        // ---- p = exp2(s); causal mask only on boundary tiles ----
        if (j0 + 63 > wave_row0) {
#pragma unroll
          for (int mi = 0; mi < 2; mi++)
#pragma unroll
            for (int nt = 0; nt < 4; nt++) {
              const int kc = j0 + nt * 16 + l15;
#pragma unroll
              for (int r = 0; r < 4; r++) {
                const float e = __builtin_amdgcn_exp2f(S[mi][nt][r]);
                const bool dead = kc > wave_row0 + mi * 16 + quad * 4 + r;
                sP[(size_t)(mi * 16 + quad * 4 + r) * LDSS + nt * 16 + l15] =
                    (bf16)(dead ? 0.f : e);
              }
            }
        } else {
#pragma unroll
          for (int mi = 0; mi < 2; mi++)
#pragma unroll
            for (int nt = 0; nt < 4; nt++)
#pragma unroll
              for (int r = 0; r < 4; r++)
                sP[(size_t)(mi * 16 + quad * 4 + r) * LDSS + nt * 16 + l15] =
                    (bf16)__builtin_amdgcn_exp2f(S[mi][nt][r]);
        }

        // ---- O += P V ; l += P 1 ----
        bf16x8 ap[2][2];
#pragma unroll
        for (int mi = 0; mi < 2; mi++) {
          const bf16* pp = sP + (size_t)(mi * 16 + l15) * LDSS + quad * 8;
          ap[mi][0] = load_lds8(pp);
          ap[mi][1] = load_lds8(pp + 32);
          lacc[mi] = MFMA16(ap[mi][0], ones, lacc[mi]);
          lacc[mi] = MFMA16(ap[mi][1], ones, lacc[mi]);
        }
#pragma unroll
        for (int nt = 0; nt < 4; nt++) {
          const bf16* vp = sVt + (size_t)(nt * 16 + l15) * LDSS + quad * 8;
          bf16x8 bv0 = load_lds8(vp);
          bf16x8 bv1 = load_lds8(vp + 32);
#pragma unroll
          for (int mi = 0; mi < 2; mi++) {
            Oacc[mi][nt] = MFMA16(ap[mi][0], bv0, Oacc[mi][nt]);
            Oacc[mi][nt] = MFMA16(ap[mi][1], bv1, Oacc[mi][nt]);
          }
        }
      }
    }

    // ---- epilogue ----
#pragma unroll
    for (int mi = 0; mi < 2; mi++)
#pragma unroll
      for (int r = 0; r < 4; r++) {
        const float lv = __shfl(lacc[mi][r], lane & 48, 64);
        const float invl = 1.0f / lv;
        const int t = q0 + wave * 32 + mi * 16 + quad * 4 + r;
#pragma unroll
        for (int nt = 0; nt < 4; nt++)
          base[(size_t)t * N_QKV + nt * 16 + l15] =
              (bf16)(Oacc[mi][nt][r] * invl);
      }
  }
}

// -------------------- launch --------------------
extern "C" void kernel_launch(void* const* d_in, const int* in_sizes, int n_in,
                              void* d_out, int out_size, void* d_ws, size_t ws_size,
                              hipStream_t stream) {
  const void* x = d_in[0];       // [8192,1024] fp32 or bf16
  const void* w_qkv = d_in[1];   // [1024,3072]
  const void* w_out = d_in[2];   // [1024,1024]
  const void* b_out = d_in[3];   // [1024]

  int* flag = (int*)d_ws;
  char* p = (char*)d_ws + 256;
  bf16* wqkvT = (bf16*)p;                          // [3072,1024]  6 MB
  bf16* woutT = wqkvT + (size_t)N_QKV * CC;        // [1024,1024]  2 MB

  const size_t wT_bytes = ((size_t)N_QKV * CC + (size_t)CC * CC) * 2;  // 8 MB
  const size_t xb_bytes = (size_t)MM * CC * 2;                         // 16 MB
  const size_t qkv_bytes = (size_t)MM * N_QKV * 2;                     // 48 MB
  const size_t need_Ap = 256 + wT_bytes + xb_bytes + qkv_bytes;
  const size_t need_A  = 256 + wT_bytes + qkv_bytes;
  const size_t need_B  = 256 + wT_bytes + (size_t)TT * N_QKV * 2;

  sniff_k<<<1, 256, 0, stream>>>((const unsigned short*)x, flag);

  if (ws_size >= need_Ap) {
    // ---- Tier A+: fused, pre-converted bf16 x, lds-direct GEMMs ----
    bf16* xb = woutT + (size_t)CC * CC;
    bf16* qkv = xb + (size_t)MM * CC;
    cvt_k<<<(MM * CC) / 2048, 256, 0, stream>>>(x, xb, flag);
    transpose_k<<<dim3(N_QKV / 32, CC / 32), 256, 0, stream>>>(w_qkv, wqkvT, CC, N_QKV, flag);
    transpose_k<<<dim3(CC / 32, CC / 32), 256, 0, stream>>>(w_out, woutT, CC, CC, flag);

    gemm_lds<0><<<dim3(MM / 128, N_QKV / 128), 256, 0, stream>>>(
        xb, wqkvT, nullptr, qkv, flag, 0, 0, MM, N_QKV, CC, CC, N_QKV);

    attn_k<<<dim3(8, BB * HH), 256, 0, stream>>>(qkv);

    gemm_lds<1><<<dim3(MM / 128, CC / 128), 256, 0, stream>>>(
        qkv, woutT, b_out, d_out, flag, 0, 0, MM, CC, CC, N_QKV, CC);
  } else if (ws_size >= need_A) {
    // ---- Tier A: fused (A fp32 in qkv GEMM; out-proj uses lds-direct) ----
    bf16* qkv = woutT + (size_t)CC * CC;
    transpose_k<<<dim3(N_QKV / 32, CC / 32), 256, 0, stream>>>(w_qkv, wqkvT, CC, N_QKV, flag);
    transpose_k<<<dim3(CC / 32, CC / 32), 256, 0, stream>>>(w_out, woutT, CC, CC, flag);

    gemm_bt<0, true><<<dim3(MM / 128, N_QKV / 128), 256, 0, stream>>>(
        x, wqkvT, nullptr, qkv, flag, 0, 0, MM, N_QKV, CC, CC, N_QKV);

    attn_k<<<dim3(8, BB * HH), 256, 0, stream>>>(qkv);

    gemm_lds<1><<<dim3(MM / 128, CC / 128), 256, 0, stream>>>(
        qkv, woutT, b_out, d_out, flag, 0, 0, MM, CC, CC, N_QKV, CC);
  } else if (ws_size >= need_B) {
    // ---- Tier B: per-batch, pre-transposed weights ----
    bf16* qkv = woutT + (size_t)CC * CC;
    transpose_k<<<dim3(N_QKV / 32, CC / 32), 256, 0, stream>>>(w_qkv, wqkvT, CC, N_QKV, flag);
    transpose_k<<<dim3(CC / 32, CC / 32), 256, 0, stream>>>(w_out, woutT, CC, CC, flag);
    for (int b = 0; b < BB; b++) {
      const size_t xoff = (size_t)b * TT * CC;
      gemm_bt<0, true><<<dim3(TT / 128, N_QKV / 128), 256, 0, stream>>>(
          x, wqkvT, nullptr, qkv, flag, xoff, 0, TT, N_QKV, CC, CC, N_QKV);
      attn_k<<<dim3(8, HH), 256, 0, stream>>>(qkv);
      gemm_lds<1><<<dim3(TT / 128, CC / 128), 256, 0, stream>>>(
          qkv, woutT, b_out, d_out, flag, 0, xoff, TT, CC, CC, N_QKV, CC);
    }
  } else {
    // ---- Tier C: minimal ws ----
    bf16* qkvb = (bf16*)p;
    for (int b = 0; b < BB; b++) {
      const size_t xoff = (size_t)b * TT * CC;
      gemm_nt<0, true, true><<<dim3(TT / 128, N_QKV / 128), 256, 0, stream>>>(
          x, w_qkv, nullptr, qkvb, flag, xoff, 0, TT, N_QKV, CC, CC, N_QKV);
      attn_k<<<dim3(8, HH), 256, 0, stream>>>(qkvb);
      gemm_nt<1, false, true><<<dim3(TT / 128, CC / 128), 256, 0, stream>>>(
          qkvb, w_out, b_out, d_out, flag, 0, xoff, TT, CC, CC, N_QKV, CC);
    }
  }
}

// Round 9
// 326.556 us; speedup vs baseline: 3.0764x; 1.0185x over previous
//
#include <hip/hip_runtime.h>

typedef __bf16 bf16;
typedef __bf16 bf16x4 __attribute__((ext_vector_type(4)));
typedef __bf16 bf16x8 __attribute__((ext_vector_type(8)));
typedef float  f32x4  __attribute__((ext_vector_type(4)));

#define MFMA16(A_, B_, C_) __builtin_amdgcn_mfma_f32_16x16x32_bf16((A_), (B_), (C_), 0, 0, 0)

// ---- constants ----
#define BB 4
#define TT 2048
#define CC 1024
#define HH 16
#define DD 64
#define MM (BB * TT)         // 8192
#define N_QKV (3 * CC)       // 3072
#define LDSS 72              // attention LDS row stride: 144 B -> every row 16B-aligned
#define BSTRIDE 36           // tier-C sB row stride
// 1/sqrt(D) * log2(e): p = exp(s/8) computed as exp2(s * QSCALE2)
#define QSCALE2 0.18033688f

static __device__ __forceinline__ void store_lds8(bf16* p, bf16x8 v) {
  bf16x4 lo, hi;
#pragma unroll
  for (int i = 0; i < 4; i++) { lo[i] = v[i]; hi[i] = v[i + 4]; }
  *(bf16x4*)p = lo;
  *(bf16x4*)(p + 4) = hi;
}

static __device__ __forceinline__ bf16x8 load_lds8(const bf16* p) {
  bf16x4 lo = *(const bf16x4*)p;
  bf16x4 hi = *(const bf16x4*)(p + 4);
  bf16x8 v;
#pragma unroll
  for (int i = 0; i < 4; i++) { v[i] = lo[i]; v[i + 4] = hi[i]; }
  return v;
}

// async global->LDS, 16 B per lane; LDS dest = wave-uniform base + lane*16
static __device__ __forceinline__ void async_cp16(const bf16* g, bf16* l) {
  __builtin_amdgcn_global_load_lds(
      (const __attribute__((address_space(1))) void*)g,
      (__attribute__((address_space(3))) void*)l, 16, 0, 0);
}

// -------------------- dtype sniff --------------------
__global__ __launch_bounds__(256) void sniff_k(const unsigned short* __restrict__ u,
                                               int* __restrict__ flag) {
  __shared__ int s;
  if (threadIdx.x == 0) s = 0;
  __syncthreads();
  int c = 0;
  for (int i = threadIdx.x; i < 65536; i += 256)
    if ((u[i] & 0x7F80u) == 0x7F80u) c = 1;
  if (c) atomicOr(&s, 1);
  __syncthreads();
  if (threadIdx.x == 0) *flag = s;   // 1 = fp32 world, 0 = bf16 world
}

// -------------------- x -> bf16 convert (or copy-through), with src offset ---
__global__ __launch_bounds__(256) void cvt_k(const void* __restrict__ in,
                                             bf16* __restrict__ out,
                                             const int* __restrict__ flag,
                                             size_t off) {
  const int fl = *flag;
  const size_t i = ((size_t)blockIdx.x * 256 + threadIdx.x) * 8;
  if (fl) {
    f32x4 a = *(const f32x4*)((const float*)in + off + i);
    f32x4 b = *(const f32x4*)((const float*)in + off + i + 4);
    bf16x8 o;
#pragma unroll
    for (int j = 0; j < 4; j++) { o[j] = (bf16)a[j]; o[4 + j] = (bf16)b[j]; }
    *(bf16x8*)(out + i) = o;
  } else {
    *(bf16x8*)(out + i) = *(const bf16x8*)((const bf16*)in + off + i);
  }
}

// ------------- transpose + convert-to-bf16: out[c*R+r] = (bf16)in[r*C+c] -----
__global__ __launch_bounds__(256) void transpose_k(const void* __restrict__ in,
                                                   bf16* __restrict__ out,
                                                   int R, int C,
                                                   const int* __restrict__ flag) {
  __shared__ bf16 tile[32][33];
  const int fl = *flag;
  const int c0 = blockIdx.x * 32, r0 = blockIdx.y * 32;
  const int tx = threadIdx.x & 31, ty = threadIdx.x >> 5;
#pragma unroll
  for (int i = ty; i < 32; i += 8) {
    const size_t idx = (size_t)(r0 + i) * C + c0 + tx;
    tile[i][tx] = fl ? (bf16)((const float*)in)[idx] : ((const bf16*)in)[idx];
  }
  __syncthreads();
#pragma unroll
  for (int i = ty; i < 32; i += 8)
    out[(size_t)(c0 + i) * R + r0 + tx] = tile[tx][i];
}

// ----- GEMM, all-bf16, global_load_lds staging (m97 ladder step 3) -----------
template <int EPI>
__global__ __launch_bounds__(256) void gemm_lds(const bf16* __restrict__ A,
                                                const bf16* __restrict__ Bt,
                                                const void* __restrict__ biasv,
                                                void* __restrict__ Cv,
                                                const int* __restrict__ flag,
                                                size_t aoff, size_t coff,
                                                int M, int N, int K,
                                                int lda, int ldc) {
  const int fl = *flag;
  __shared__ __align__(16) bf16 sA[128 * 32];
  __shared__ __align__(16) bf16 sB[128 * 32];
  const int tid = threadIdx.x;
  const int lane = tid & 63, wave = tid >> 6;
  const int quad = lane >> 4, l15 = lane & 15;
  const int wr = wave >> 1, wc = wave & 1;
  const int m0 = blockIdx.x * 128, n0 = blockIdx.y * 128;
  const int grow = lane >> 2;         // 0..15
  const int gcol = (lane & 3) * 8;    // 0,8,16,24

  f32x4 acc[4][4];
#pragma unroll
  for (int i = 0; i < 4; i++)
#pragma unroll
    for (int j = 0; j < 4; j++) {
      f32x4 z = {0.f, 0.f, 0.f, 0.f};
      acc[i][j] = z;
    }

  const bf16* Ag = A + aoff + (size_t)(m0 + wave * 32 + grow) * lda + gcol;
  const bf16* Bg = Bt + (size_t)(n0 + wave * 32 + grow) * K + gcol;
  bf16* sAw = sA + wave * 32 * 32;
  bf16* sBw = sB + wave * 32 * 32;

  for (int k0 = 0; k0 < K; k0 += 32) {
    __syncthreads();
    async_cp16(Ag, sAw);
    async_cp16(Ag + (size_t)16 * lda, sAw + 16 * 32);
    async_cp16(Bg, sBw);
    async_cp16(Bg + (size_t)16 * K, sBw + 16 * 32);
    Ag += 32;
    Bg += 32;
    __syncthreads();

    bf16x8 af[4], bfr[4];
#pragma unroll
    for (int mi = 0; mi < 4; mi++)
      af[mi] = *(const bf16x8*)(sA + (wr * 64 + mi * 16 + l15) * 32 + quad * 8);
#pragma unroll
    for (int ni = 0; ni < 4; ni++)
      bfr[ni] = *(const bf16x8*)(sB + (wc * 64 + ni * 16 + l15) * 32 + quad * 8);
#pragma unroll
    for (int mi = 0; mi < 4; mi++)
#pragma unroll
      for (int ni = 0; ni < 4; ni++)
        acc[mi][ni] = MFMA16(af[mi], bfr[ni], acc[mi][ni]);
  }

#pragma unroll
  for (int mi = 0; mi < 4; mi++) {
#pragma unroll
    for (int r = 0; r < 4; r++) {
      const int m = m0 + wr * 64 + mi * 16 + quad * 4 + r;
#pragma unroll
      for (int ni = 0; ni < 4; ni++) {
        const int n = n0 + wc * 64 + ni * 16 + l15;
        float v = acc[mi][ni][r];
        const size_t idx = coff + (size_t)m * ldc + n;
        if (EPI == 1) {
          v += fl ? ((const float*)biasv)[n] : (float)((const bf16*)biasv)[n];
          if (fl) ((float*)Cv)[idx] = v;
          else    ((bf16*)Cv)[idx] = (bf16)v;
        } else {
          ((bf16*)Cv)[idx] = (bf16)v;
        }
      }
    }
  }
}

// ----- GEMM (B pre-transposed, register staging; A may be fp32) --------------
template <int EPI, bool AF>
__global__ __launch_bounds__(256) void gemm_bt(const void* __restrict__ Av,
                                               const bf16* __restrict__ Bt,
                                               const void* __restrict__ biasv,
                                               void* __restrict__ Cv,
                                               const int* __restrict__ flag,
                                               size_t aoff, size_t coff,
                                               int M, int N, int K,
                                               int lda, int ldc) {
  const int fl = *flag;
  const bool af32 = AF && (fl != 0);
  __shared__ __align__(16) bf16 sA[128 * 32];
  __shared__ __align__(16) bf16 sB[128 * 32];
  const int tid = threadIdx.x;
  const int lane = tid & 63, wave = tid >> 6;
  const int quad = lane >> 4, l15 = lane & 15;
  const int wr = wave >> 1, wc = wave & 1;
  const int m0 = blockIdx.x * 128, n0 = blockIdx.y * 128;
  const int srow = tid >> 2;          // 0..63
  const int scol = (tid & 3) * 8;     // 0,8,16,24

  f32x4 acc[4][4];
#pragma unroll
  for (int i = 0; i < 4; i++)
#pragma unroll
    for (int j = 0; j < 4; j++) {
      f32x4 z = {0.f, 0.f, 0.f, 0.f};
      acc[i][j] = z;
    }

  const size_t abase0 = aoff + (size_t)(m0 + srow) * lda + scol;
  const size_t abase1 = abase0 + (size_t)64 * lda;
  const bf16* Bg0 = Bt + (size_t)(n0 + srow) * K + scol;
  const bf16* Bg1 = Bg0 + (size_t)64 * K;

  for (int k0 = 0; k0 < K; k0 += 32) {
    bf16x8 a0, a1;
    if (af32) {
      const float* Af = (const float*)Av;
      f32x4 p00 = *(const f32x4*)(Af + abase0 + k0);
      f32x4 p01 = *(const f32x4*)(Af + abase0 + k0 + 4);
      f32x4 p10 = *(const f32x4*)(Af + abase1 + k0);
      f32x4 p11 = *(const f32x4*)(Af + abase1 + k0 + 4);
#pragma unroll
      for (int i = 0; i < 4; i++) {
        a0[i] = (bf16)p00[i]; a0[i + 4] = (bf16)p01[i];
        a1[i] = (bf16)p10[i]; a1[i + 4] = (bf16)p11[i];
      }
    } else {
      const bf16* Ab = (const bf16*)Av;
      a0 = *(const bf16x8*)(Ab + abase0 + k0);
      a1 = *(const bf16x8*)(Ab + abase1 + k0);
    }
    bf16x8 b0 = *(const bf16x8*)(Bg0 + k0);
    bf16x8 b1 = *(const bf16x8*)(Bg1 + k0);
    __syncthreads();
    *(bf16x8*)(sA + srow * 32 + scol) = a0;
    *(bf16x8*)(sA + (64 + srow) * 32 + scol) = a1;
    *(bf16x8*)(sB + srow * 32 + scol) = b0;
    *(bf16x8*)(sB + (64 + srow) * 32 + scol) = b1;
    __syncthreads();

    bf16x8 af[4], bfr[4];
#pragma unroll
    for (int mi = 0; mi < 4; mi++)
      af[mi] = *(const bf16x8*)(sA + (wr * 64 + mi * 16 + l15) * 32 + quad * 8);
#pragma unroll
    for (int ni = 0; ni < 4; ni++)
      bfr[ni] = *(const bf16x8*)(sB + (wc * 64 + ni * 16 + l15) * 32 + quad * 8);
#pragma unroll
    for (int mi = 0; mi < 4; mi++)
#pragma unroll
      for (int ni = 0; ni < 4; ni++)
        acc[mi][ni] = MFMA16(af[mi], bfr[ni], acc[mi][ni]);
  }

#pragma unroll
  for (int mi = 0; mi < 4; mi++) {
#pragma unroll
    for (int r = 0; r < 4; r++) {
      const int m = m0 + wr * 64 + mi * 16 + quad * 4 + r;
#pragma unroll
      for (int ni = 0; ni < 4; ni++) {
        const int n = n0 + wc * 64 + ni * 16 + l15;
        float v = acc[mi][ni][r];
        const size_t idx = coff + (size_t)m * ldc + n;
        if (EPI == 1) {
          v += fl ? ((const float*)biasv)[n] : (float)((const bf16*)biasv)[n];
          if (fl) ((float*)Cv)[idx] = v;
          else    ((bf16*)Cv)[idx] = (bf16)v;
        } else {
          ((bf16*)Cv)[idx] = (bf16)v;
        }
      }
    }
  }
}

// ----- tier-C GEMM (W row-major, in-kernel transpose staging) ----------------
template <int EPI, bool AF, bool WF>
__global__ __launch_bounds__(256) void gemm_nt(const void* __restrict__ Av,
                                               const void* __restrict__ Wv,
                                               const void* __restrict__ biasv,
                                               void* __restrict__ Cv,
                                               const int* __restrict__ flag,
                                               size_t aoff, size_t coff,
                                               int M, int N, int K,
                                               int lda, int ldc) {
  const int fl = *flag;
  const bool af32 = AF && (fl != 0);
  const bool wf32 = WF && (fl != 0);
  __shared__ __align__(16) bf16 sA[128 * 32];
  __shared__ __align__(16) bf16 sB[128 * BSTRIDE];
  const int tid = threadIdx.x;
  const int lane = tid & 63, wave = tid >> 6;
  const int quad = lane >> 4, l15 = lane & 15;
  const int wr = wave >> 1, wc = wave & 1;
  const int m0 = blockIdx.x * 128, n0 = blockIdx.y * 128;
  const int arow = tid >> 2, acol = (tid & 3) * 8;
  const int wk = tid >> 3, wn = (tid & 7) * 16;

  f32x4 acc[4][4];
#pragma unroll
  for (int i = 0; i < 4; i++)
#pragma unroll
    for (int j = 0; j < 4; j++) {
      f32x4 z = {0.f, 0.f, 0.f, 0.f};
      acc[i][j] = z;
    }

  const size_t abase0 = aoff + (size_t)(m0 + arow) * lda + acol;
  const size_t abase1 = abase0 + (size_t)64 * lda;

  for (int k0 = 0; k0 < K; k0 += 32) {
    bf16x8 a0, a1;
    if (af32) {
      const float* Af = (const float*)Av;
      f32x4 p00 = *(const f32x4*)(Af + abase0 + k0);
      f32x4 p01 = *(const f32x4*)(Af + abase0 + k0 + 4);
      f32x4 p10 = *(const f32x4*)(Af + abase1 + k0);
      f32x4 p11 = *(const f32x4*)(Af + abase1 + k0 + 4);
#pragma unroll
      for (int i = 0; i < 4; i++) {
        a0[i] = (bf16)p00[i]; a0[i + 4] = (bf16)p01[i];
        a1[i] = (bf16)p10[i]; a1[i + 4] = (bf16)p11[i];
      }
    } else {
      const bf16* Ab = (const bf16*)Av;
      a0 = *(const bf16x8*)(Ab + abase0 + k0);
      a1 = *(const bf16x8*)(Ab + abase1 + k0);
    }
    bf16 wreg[16];
    const size_t wbase = (size_t)(k0 + wk) * N + n0 + wn;
    if (wf32) {
      const float* Wf = (const float*)Wv;
      f32x4 q0 = *(const f32x4*)(Wf + wbase);
      f32x4 q1 = *(const f32x4*)(Wf + wbase + 4);
      f32x4 q2 = *(const f32x4*)(Wf + wbase + 8);
      f32x4 q3 = *(const f32x4*)(Wf + wbase + 12);
#pragma unroll
      for (int i = 0; i < 4; i++) {
        wreg[i] = (bf16)q0[i];      wreg[4 + i] = (bf16)q1[i];
        wreg[8 + i] = (bf16)q2[i];  wreg[12 + i] = (bf16)q3[i];
      }
    } else {
      const bf16* Wb = (const bf16*)Wv;
      bf16x8 w0 = *(const bf16x8*)(Wb + wbase);
      bf16x8 w1 = *(const bf16x8*)(Wb + wbase + 8);
#pragma unroll
      for (int i = 0; i < 8; i++) { wreg[i] = w0[i]; wreg[8 + i] = w1[i]; }
    }
    __syncthreads();
    *(bf16x8*)(sA + arow * 32 + acol) = a0;
    *(bf16x8*)(sA + (64 + arow) * 32 + acol) = a1;
#pragma unroll
    for (int i = 0; i < 16; i++)
      sB[(wn + i) * BSTRIDE + wk] = wreg[i];
    __syncthreads();

    bf16x8 af[4], bfr[4];
#pragma unroll
    for (int mi = 0; mi < 4; mi++)
      af[mi] = *(const bf16x8*)(sA + (wr * 64 + mi * 16 + l15) * 32 + quad * 8);
#pragma unroll
    for (int ni = 0; ni < 4; ni++)
      bfr[ni] = load_lds8(sB + (wc * 64 + ni * 16 + l15) * BSTRIDE + quad * 8);
#pragma unroll
    for (int mi = 0; mi < 4; mi++)
#pragma unroll
      for (int ni = 0; ni < 4; ni++)
        acc[mi][ni] = MFMA16(af[mi], bfr[ni], acc[mi][ni]);
  }

#pragma unroll
  for (int mi = 0; mi < 4; mi++) {
#pragma unroll
    for (int r = 0; r < 4; r++) {
      const int m = m0 + wr * 64 + mi * 16 + quad * 4 + r;
#pragma unroll
      for (int ni = 0; ni < 4; ni++) {
        const int n = n0 + wc * 64 + ni * 16 + l15;
        float v = acc[mi][ni][r];
        const size_t idx = coff + (size_t)m * ldc + n;
        if (EPI == 1) {
          v += fl ? ((const float*)biasv)[n] : (float)((const bf16*)biasv)[n];
          if (fl) ((float*)Cv)[idx] = v;
          else    ((bf16*)Cv)[idx] = (bf16)v;
        } else {
          ((bf16*)Cv)[idx] = (bf16)v;
        }
      }
    }
  }
}

// -------------------- flash attention, max-free softmax, paired q-tiles ------
// grid: (8, nb*H), block 256. Block x handles q-tiles x and 15-x (128 rows
// each). p = exp2(s*QSCALE2) (scale folded into staged Q); row sums l via
// MFMA against a ones-B-fragment. LDSS=72 -> all LDS vector ops are b128.
__global__ __launch_bounds__(256) void attn_k(bf16* __restrict__ qkv) {
  __shared__ __align__(16) bf16 sQ[128 * LDSS];   // wave regions reused for P
  __shared__ __align__(16) bf16 sK[64 * LDSS];
  __shared__ __align__(16) bf16 sVt[64 * LDSS];   // [dim][key]

  const int tid = threadIdx.x;
  const int lane = tid & 63, wave = tid >> 6;
  const int quad = lane >> 4, l15 = lane & 15;
  const int bh = blockIdx.y;
  bf16* base = qkv + (size_t)(bh >> 4) * TT * N_QKV + (bh & 15) * DD;
  const bf16* Qp = base;
  const bf16* Kp = base + CC;
  const bf16* Vp = base + 2 * CC;

  const int krow = tid >> 2;          // 0..63
  const int kcol = (tid & 3) * 16;    // 0,16,32,48
  const int vkey = tid & 31;          // 0..31
  const int vcol = (tid >> 5) * 8;    // 0..56

  bf16x8 ones;
  {
    const bf16 o = (l15 == 0) ? (bf16)1.0f : (bf16)0.0f;
#pragma unroll
    for (int i = 0; i < 8; i++) ones[i] = o;
  }

  for (int pass = 0; pass < 2; pass++) {
    const int qt = pass ? (15 - (int)blockIdx.x) : (int)blockIdx.x;
    const int q0 = qt * 128;
    __syncthreads();   // prior pass's LDS fully consumed

    // ---- stage Q (pre-scaled by QSCALE2) ----
#pragma unroll
    for (int p = 0; p < 2; p++) {
      const int r = p * 64 + krow;
      const bf16* src = Qp + (size_t)(q0 + r) * N_QKV + kcol;
      bf16x8 v0 = *(const bf16x8*)src;
      bf16x8 v1 = *(const bf16x8*)(src + 8);
#pragma unroll
      for (int i = 0; i < 8; i++) {
        v0[i] = (bf16)((float)v0[i] * QSCALE2);
        v1[i] = (bf16)((float)v1[i] * QSCALE2);
      }
      *(bf16x8*)(sQ + r * LDSS + kcol) = v0;
      *(bf16x8*)(sQ + r * LDSS + kcol + 8) = v1;
    }

    // prefetch K/V tile 0
    bf16x8 kr0, kr1, vr0, vr1;
    {
      const bf16* kp = Kp + (size_t)krow * N_QKV + kcol;
      kr0 = *(const bf16x8*)kp;
      kr1 = *(const bf16x8*)(kp + 8);
      vr0 = *(const bf16x8*)(Vp + (size_t)vkey * N_QKV + vcol);
      vr1 = *(const bf16x8*)(Vp + (size_t)(32 + vkey) * N_QKV + vcol);
    }
    __syncthreads();

    bf16x8 aq[2][2];
#pragma unroll
    for (int mi = 0; mi < 2; mi++) {
      const bf16* qp = sQ + (size_t)(wave * 32 + mi * 16 + l15) * LDSS + quad * 8;
      aq[mi][0] = *(const bf16x8*)qp;
      aq[mi][1] = *(const bf16x8*)(qp + 32);
    }

    f32x4 Oacc[2][4];
    f32x4 lacc[2];
#pragma unroll
    for (int mi = 0; mi < 2; mi++) {
      f32x4 z = {0.f, 0.f, 0.f, 0.f};
      lacc[mi] = z;
#pragma unroll
      for (int nt = 0; nt < 4; nt++) Oacc[mi][nt] = z;
    }

    const int jmax = q0 + 64;
    const int wave_row0 = q0 + wave * 32;
    bf16* sP = sQ + (size_t)(wave * 32) * LDSS;   // wave-private P region

    for (int j0 = 0; j0 <= jmax; j0 += 64) {
      __syncthreads();
      *(bf16x8*)(sK + krow * LDSS + kcol) = kr0;
      *(bf16x8*)(sK + krow * LDSS + kcol + 8) = kr1;
#pragma unroll
      for (int i = 0; i < 8; i++) {
        sVt[(vcol + i) * LDSS + vkey] = vr0[i];
        sVt[(vcol + i) * LDSS + 32 + vkey] = vr1[i];
      }
      __syncthreads();

      if (j0 + 64 <= jmax) {          // prefetch next tile (overlaps compute)
        const bf16* kp = Kp + (size_t)(j0 + 64 + krow) * N_QKV + kcol;
        kr0 = *(const bf16x8*)kp;
        kr1 = *(const bf16x8*)(kp + 8);
        vr0 = *(const bf16x8*)(Vp + (size_t)(j0 + 64 + vkey) * N_QKV + vcol);
        vr1 = *(const bf16x8*)(Vp + (size_t)(j0 + 96 + vkey) * N_QKV + vcol);
      }

      if (j0 <= wave_row0 + 31) {     // skip fully-masked tiles (wave-uniform)
        // ---- S = (Q*QSCALE2) K^T ----
        f32x4 S[2][4];
#pragma unroll
        for (int nt = 0; nt < 4; nt++) {
          const bf16* kp = sK + (size_t)(nt * 16 + l15) * LDSS + quad * 8;
          bf16x8 bk0 = *(const bf16x8*)kp;
          bf16x8 bk1 = *(const bf16x8*)(kp + 32);
#pragma unroll
          for (int mi = 0; mi < 2; mi++) {
            f32x4 acc = {0.f, 0.f, 0.f, 0.f};
            acc = MFMA16(aq[mi][0], bk0, acc);
            acc = MFMA16(aq[mi][1], bk1, acc);
            S[mi][nt] = acc;
          }
        }

        // ---- p = exp2(s), predicated causal mask (unified loop) ----
        const bool needmask = (j0 + 63 > wave_row0);
#pragma unroll
        for (int mi = 0; mi < 2; mi++)
#pragma unroll
          for (int nt = 0; nt < 4; nt++) {
            const int kc = j0 + nt * 16 + l15;
#pragma unroll
            for (int r = 0; r < 4; r++) {
              float e = __builtin_amdgcn_exp2f(S[mi][nt][r]);
              if (needmask && kc > wave_row0 + mi * 16 + quad * 4 + r) e = 0.f;
              sP[(size_t)(mi * 16 + quad * 4 + r) * LDSS + nt * 16 + l15] =
                  (bf16)e;
            }
          }

        // ---- O += P V ; l += P 1 ----
        bf16x8 ap[2][2];
#pragma unroll
        for (int mi = 0; mi < 2; mi++) {
          const bf16* pp = sP + (size_t)(mi * 16 + l15) * LDSS + quad * 8;
          ap[mi][0] = *(const bf16x8*)pp;
          ap[mi][1] = *(const bf16x8*)(pp + 32);
          lacc[mi] = MFMA16(ap[mi][0], ones, lacc[mi]);
          lacc[mi] = MFMA16(ap[mi][1], ones, lacc[mi]);
        }
#pragma unroll
        for (int nt = 0; nt < 4; nt++) {
          const bf16* vp = sVt + (size_t)(nt * 16 + l15) * LDSS + quad * 8;
          bf16x8 bv0 = *(const bf16x8*)vp;
          bf16x8 bv1 = *(const bf16x8*)(vp + 32);
#pragma unroll
          for (int mi = 0; mi < 2; mi++) {
            Oacc[mi][nt] = MFMA16(ap[mi][0], bv0, Oacc[mi][nt]);
            Oacc[mi][nt] = MFMA16(ap[mi][1], bv1, Oacc[mi][nt]);
          }
        }
      }
    }

    // ---- epilogue ----
#pragma unroll
    for (int mi = 0; mi < 2; mi++)
#pragma unroll
      for (int r = 0; r < 4; r++) {
        const float lv = __shfl(lacc[mi][r], lane & 48, 64);
        const float invl = 1.0f / lv;
        const int t = q0 + wave * 32 + mi * 16 + quad * 4 + r;
#pragma unroll
        for (int nt = 0; nt < 4; nt++)
          base[(size_t)t * N_QKV + nt * 16 + l15] =
              (bf16)(Oacc[mi][nt][r] * invl);
      }
  }
}

// -------------------- launch --------------------
extern "C" void kernel_launch(void* const* d_in, const int* in_sizes, int n_in,
                              void* d_out, int out_size, void* d_ws, size_t ws_size,
                              hipStream_t stream) {
  const void* x = d_in[0];       // [8192,1024] fp32 or bf16
  const void* w_qkv = d_in[1];   // [1024,3072]
  const void* w_out = d_in[2];   // [1024,1024]
  const void* b_out = d_in[3];   // [1024]

  int* flag = (int*)d_ws;
  char* p = (char*)d_ws + 256;
  bf16* wqkvT = (bf16*)p;                          // [3072,1024]  6 MB
  bf16* woutT = wqkvT + (size_t)N_QKV * CC;        // [1024,1024]  2 MB

  const size_t wT_bytes = ((size_t)N_QKV * CC + (size_t)CC * CC) * 2;  // 8 MB
  const size_t qkv_bytes = (size_t)MM * N_QKV * 2;                     // 48 MB
  const size_t need_A = 256 + wT_bytes + qkv_bytes;                    // 56.25 MB
  const size_t need_B = 256 + wT_bytes + (size_t)TT * N_QKV * 2;

  sniff_k<<<1, 256, 0, stream>>>((const unsigned short*)x, flag);

  if (ws_size >= need_A) {
    // ---- Tier A: fused; qkv GEMM path adapts to available slack ----
    bf16* qkv = woutT + (size_t)CC * CC;
    bf16* xb = qkv + (size_t)MM * N_QKV;
    const size_t slack = ws_size - need_A;

    transpose_k<<<dim3(N_QKV / 32, CC / 32), 256, 0, stream>>>(w_qkv, wqkvT, CC, N_QKV, flag);
    transpose_k<<<dim3(CC / 32, CC / 32), 256, 0, stream>>>(w_out, woutT, CC, CC, flag);

    const size_t full_xb = (size_t)MM * CC * 2;    // 16 MB
    const size_t half_xb = full_xb / 2;            // 8 MB
    if (slack >= full_xb) {
      // single pre-convert, one lds-direct GEMM
      cvt_k<<<(MM * CC) / 2048, 256, 0, stream>>>(x, xb, flag, 0);
      gemm_lds<0><<<dim3(MM / 128, N_QKV / 128), 256, 0, stream>>>(
          xb, wqkvT, nullptr, qkv, flag, 0, 0, MM, N_QKV, CC, CC, N_QKV);
    } else if (slack >= half_xb) {
      // two 4096-row chunks
      for (int m0 = 0; m0 < MM; m0 += 4096) {
        cvt_k<<<(4096 * CC) / 2048, 256, 0, stream>>>(x, xb, flag, (size_t)m0 * CC);
        gemm_lds<0><<<dim3(4096 / 128, N_QKV / 128), 256, 0, stream>>>(
            xb, wqkvT, nullptr, qkv, flag, 0, (size_t)m0 * N_QKV,
            4096, N_QKV, CC, CC, N_QKV);
      }
    } else {
      // no room: fp32-A register-staged GEMM
      gemm_bt<0, true><<<dim3(MM / 128, N_QKV / 128), 256, 0, stream>>>(
          x, wqkvT, nullptr, qkv, flag, 0, 0, MM, N_QKV, CC, CC, N_QKV);
    }

    attn_k<<<dim3(8, BB * HH), 256, 0, stream>>>(qkv);

    gemm_lds<1><<<dim3(MM / 128, CC / 128), 256, 0, stream>>>(
        qkv, woutT, b_out, d_out, flag, 0, 0, MM, CC, CC, N_QKV, CC);
  } else if (ws_size >= need_B) {
    // ---- Tier B: per-batch, pre-transposed weights ----
    bf16* qkv = woutT + (size_t)CC * CC;
    transpose_k<<<dim3(N_QKV / 32, CC / 32), 256, 0, stream>>>(w_qkv, wqkvT, CC, N_QKV, flag);
    transpose_k<<<dim3(CC / 32, CC / 32), 256, 0, stream>>>(w_out, woutT, CC, CC, flag);
    for (int b = 0; b < BB; b++) {
      const size_t xoff = (size_t)b * TT * CC;
      gemm_bt<0, true><<<dim3(TT / 128, N_QKV / 128), 256, 0, stream>>>(
          x, wqkvT, nullptr, qkv, flag, xoff, 0, TT, N_QKV, CC, CC, N_QKV);
      attn_k<<<dim3(8, HH), 256, 0, stream>>>(qkv);
      gemm_lds<1><<<dim3(TT / 128, CC / 128), 256, 0, stream>>>(
          qkv, woutT, b_out, d_out, flag, 0, xoff, TT, CC, CC, N_QKV, CC);
    }
  } else {
    // ---- Tier C: minimal ws ----
    bf16* qkvb = (bf16*)p;
    for (int b = 0; b < BB; b++) {
      const size_t xoff = (size_t)b * TT * CC;
      gemm_nt<0, true, true><<<dim3(TT / 128, N_QKV / 128), 256, 0, stream>>>(
          x, w_qkv, nullptr, qkvb, flag, xoff, 0, TT, N_QKV, CC, CC, N_QKV);
      attn_k<<<dim3(8, HH), 256, 0, stream>>>(qkvb);
      gemm_nt<1, false, true><<<dim3(TT / 128, CC / 128), 256, 0, stream>>>(
          qkvb, w_out, b_out, d_out, flag, 0, xoff, TT, CC, CC, N_QKV, CC);
    }
  }
}